// Round 14
// baseline (276.232 us; speedup 1.0000x reference)
//
#include <hip/hip_runtime.h>

// ChunkedSelfAttention (RoPE + per-chunk causal SDPA), MI355X gfx950.
// R14 (terminal): R12/R13 skeleton. packh P-packing (round-to-nearest, max
// correctness margin: absmax ~0.027 vs threshold 0.0825), vmax16 tree
// (exact, shorter dep chain), setprio removed from attn (m190: hurts
// barrier-lockstep structures). Merged prep + rope table unchanged.

typedef __attribute__((ext_vector_type(2)))  float     f32x2;
typedef __attribute__((ext_vector_type(4)))  float     f32x4;
typedef __attribute__((ext_vector_type(16))) float     f32x16;
typedef __attribute__((ext_vector_type(8)))  _Float16  f16x8;
typedef unsigned int   u32;
typedef unsigned short u16;
typedef __attribute__((ext_vector_type(4))) unsigned int u32x4;

#define MFMA(a, b, c) __builtin_amdgcn_mfma_f32_32x32x16_f16(a, b, c, 0, 0, 0)

constexpr int Ll = 4096;
constexpr float QSCALE = 0.08838834764831845f * 1.4426950408889634f; // 1/sqrt(128)*log2(e)

__device__ __forceinline__ f32x4 ld_f32x4(const void* p) { f32x4 v; __builtin_memcpy(&v, p, 16); return v; }
__device__ __forceinline__ f32x2 ld_f32x2(const void* p) { f32x2 v; __builtin_memcpy(&v, p, 8);  return v; }
__device__ __forceinline__ u32x4 ld_u32x4(const void* p) { u32x4 v; __builtin_memcpy(&v, p, 16); return v; }
__device__ __forceinline__ void  st_u32x4(void* p, u32x4 v) { __builtin_memcpy(p, &v, 16); }
__device__ __forceinline__ f16x8 ld_f16x8(const void* p) { f16x8 v; __builtin_memcpy(&v, p, 16); return v; }
__device__ __forceinline__ f16x8 ld_frag(const u32* dwp) {
  f16x8 v;
  __builtin_memcpy(&v, dwp, 8);
  __builtin_memcpy(((char*)&v) + 8, dwp + 2, 8);
  return v;
}
__device__ __forceinline__ u32 packh(_Float16 a, _Float16 b) {
  return (u32)__builtin_bit_cast(u16, a) | ((u32)__builtin_bit_cast(u16, b) << 16);
}

// ---- cos/sin table (verbatim R6) ----
__global__ void rope_table_k(const int* __restrict__ startp, float* __restrict__ tab) {
  int idx = blockIdx.x * 256 + threadIdx.x;
  int t = idx >> 6, hid = idx & 63;
  float a = (float)hid * (-0.14391156831212878f);
  float invf = expf(a);
  float ang = (float)(t + startp[0]) * invf;
  tab[2 * idx]     = cosf(ang);
  tab[2 * idx + 1] = sinf(ang);
}

// ---- merged prepass (verbatim R12) ----
__global__ __launch_bounds__(256)
void prep_merged_kernel(const float* __restrict__ Kg, const float* __restrict__ Vg,
                        const float* __restrict__ tab, u32* __restrict__ Kh,
                        u32* __restrict__ VT) {
  __shared__ __align__(16) u32 tile[4096];
  const int bx = blockIdx.x;
  if (bx < 65536) {
    const int R    = bx * 4 + (threadIdx.x >> 6);
    const int lane = threadIdx.x & 63;
    const int h  = R & 15;
    const int bt = R >> 4;
    const int b  = bt >> 12;
    const int t  = bt & 4095;
    const int c  = t >> 10;
    const int j  = (t >> 6) & 15;
    const int row = t & 63;
    const int GID = (b * 4 + c) * 16 + h;
    const int sw  = (row & 7) << 4;
    const int dc  = ((4 * lane) ^ sw) >> 1;
    f32x2 a = ld_f32x2(Kg + (size_t)R * 128 + dc);
    float p0 = __shfl_xor(a.x, 32);
    float p1 = __shfl_xor(a.y, 32);
    f32x4 cs = ld_f32x4(tab + (size_t)t * 128 + 2 * (dc & 63));
    const float sgn = (dc < 64) ? -1.0f : 1.0f;
    float o0 = a.x * cs.x + sgn * (p0 * cs.y);
    float o1 = a.y * cs.z + sgn * (p1 * cs.w);
    Kh[((size_t)(GID * 16 + j) * 64 + row) * 64 + lane] = packh((_Float16)o0, (_Float16)o1);
  } else {
    const int gj  = bx - 65536;
    const int GID = gj >> 4, j = gj & 15;
    const int h = GID & 15, c = (GID >> 4) & 3, b = GID >> 6;
    const int tid = threadIdx.x;
    const size_t rowbase = ((size_t)(b * 4096 + c * 1024 + j * 64)) * 16 + h;
    const int k  = tid >> 2;
    const int dq = tid & 3;
    u16* t16 = (u16*)tile;
    #pragma unroll
    for (int it = 0; it < 8; ++it) {
      int dv0 = dq * 4 + 16 * it;
      f32x4 v4 = ld_f32x4(Vg + (rowbase + (size_t)k * 16) * 128 + dv0);
      #pragma unroll
      for (int u = 0; u < 4; ++u) {
        int dv = dv0 + u;
        int ci = k ^ ((dv & 7) << 3);
        t16[dv * 64 + ci] = __builtin_bit_cast(u16, (_Float16)v4[u]);
      }
    }
    __syncthreads();
    const u32* tsrc = tile + 16 * tid;
    u32* dst = VT + (size_t)gj * 4096 + 16 * tid;
    #pragma unroll
    for (int u = 0; u < 4; ++u) st_u32x4(dst + 4 * u, ld_u32x4(tsrc + 4 * u));
  }
}

// ================= main attention (R6 skeleton, no setprio, packh) =================
__global__ __launch_bounds__(512, 2)
void attn_f16_k(const float* __restrict__ Qg, const u32* __restrict__ Kh,
                const u32* __restrict__ VT, float* __restrict__ Og,
                const float* __restrict__ tab) {
  __shared__ __align__(16) u32 lds[2 * 8192];   // 64 KB, double-buffered

  const int bx  = blockIdx.x;
  const int h   = bx & 15;
  const int p   = (bx >> 4) & 1;
  const int c   = (bx >> 5) & 3;
  const int b   = bx >> 7;
  const int tid = threadIdx.x;
  const int w   = tid >> 6;
  const int lane= tid & 63;
  const int l31 = lane & 31;
  const int lg2 = lane >> 5;

  const size_t cbase = (size_t)(b * Ll + c * 1024);
  const size_t hoff  = (size_t)h * 128;
  const int tb  = c * 1024;
  const int GID = (b * 4 + c) * 16 + h;
  const u32* khg = Kh + (size_t)GID * 16 * 4096;
  const u32* vtg = VT + (size_t)GID * 16 * 4096;

  u32x4 stg[4];
  auto issue = [&](int j) {
    #pragma unroll
    for (int i = 0; i < 4; ++i) {
      int ch = w + 8 * i;                // 32 chunks of 1 KB: 0..15 K, 16..31 VT
      const u32* src = (ch < 16) ? (khg + (size_t)j * 4096 + ch * 256 + 4 * lane)
                                 : (vtg + (size_t)j * 4096 + (ch - 16) * 256 + 4 * lane);
      stg[i] = ld_u32x4(src);
    }
  };
  auto store_stage = [&](int s) {
    u32* dst0 = lds + (size_t)s * 8192;
    #pragma unroll
    for (int i = 0; i < 4; ++i) {
      int ch = w + 8 * i;
      st_u32x4(dst0 + ch * 256 + 4 * lane, stg[i]);
    }
  };

  auto vmax16 = [](const f32x16& S) {
    float a0 = fmaxf(S[0], S[1]),   a1 = fmaxf(S[2], S[3]);
    float a2 = fmaxf(S[4], S[5]),   a3 = fmaxf(S[6], S[7]);
    float a4 = fmaxf(S[8], S[9]),   a5 = fmaxf(S[10], S[11]);
    float a6 = fmaxf(S[12], S[13]), a7 = fmaxf(S[14], S[15]);
    float b0 = fmaxf(a0, a1), b1 = fmaxf(a2, a3);
    float b2 = fmaxf(a4, a5), b3 = fmaxf(a6, a7);
    return fmaxf(fmaxf(b0, b1), fmaxf(b2, b3));
  };

  #pragma unroll 1
  for (int sp = 0; sp < 2; ++sp) {
    const int qs = sp ? p : (3 - p);            // heavy strip first
    const int qrow = qs * 256 + w * 32 + l31;

    // ---------- Q prologue: load f32, rope, scale, f16 ----------
    const float* qbase = Qg + (cbase + qrow) * 2048 + hoff;
    float xq[8][8];
    #pragma unroll
    for (int ds = 0; ds < 8; ++ds) {
      const float* ptr = qbase + ds * 16 + lg2 * 8;
      f32x4 v0 = ld_f32x4(ptr);
      f32x4 v1 = ld_f32x4(ptr + 4);
      xq[ds][0]=v0.x; xq[ds][1]=v0.y; xq[ds][2]=v0.z; xq[ds][3]=v0.w;
      xq[ds][4]=v1.x; xq[ds][5]=v1.y; xq[ds][6]=v1.z; xq[ds][7]=v1.w;
    }
    const float* trowq = tab + (size_t)(tb + qrow) * 128 + lg2 * 16;
    #pragma unroll
    for (int ds = 0; ds < 4; ++ds) {
      #pragma unroll
      for (int i2 = 0; i2 < 4; ++i2) {
        f32x4 cs = ld_f32x4(trowq + ds * 32 + i2 * 4);
        int i0 = 2 * i2;
        float a0 = xq[ds][i0],     b0 = xq[ds + 4][i0];
        xq[ds][i0]     = a0 * cs.x - b0 * cs.y;
        xq[ds + 4][i0] = b0 * cs.x + a0 * cs.y;
        float a1 = xq[ds][i0 + 1], b1 = xq[ds + 4][i0 + 1];
        xq[ds][i0 + 1]     = a1 * cs.z - b1 * cs.w;
        xq[ds + 4][i0 + 1] = b1 * cs.z + a1 * cs.w;
      }
    }
    f16x8 qh[8];
    #pragma unroll
    for (int ds = 0; ds < 8; ++ds)
      #pragma unroll
      for (int i = 0; i < 8; ++i)
        qh[ds][i] = (_Float16)(xq[ds][i] * QSCALE);

    // ---------- state ----------
    f32x16 O[4];
    #pragma unroll
    for (int n = 0; n < 4; ++n) O[n] = (f32x16)0.0f;
    float m2 = -1e30f, lsum = 0.0f;
    const int  nt    = 4 * (qs + 1);
    const int  jmaxw = 4 * qs + (w >> 1);
    const bool oddw  = w & 1;

    issue(0);
    store_stage(0);
    __syncthreads();

    for (int j = 0; j < nt; ++j) {
      const int s = j & 1;
      const bool more = (j + 1 < nt);
      if (more) issue(j + 1);          // global loads fly under compute

      if (j <= jmaxw) {
        const bool full = oddw || (j < jmaxw);
        const u32* KB = lds + (size_t)s * 8192;
        const u32* VB = KB + 4096;
        const u32* kr0 = KB + (size_t)l31 * 64;
        const u32* kr1 = kr0 + 32 * 64;
        const int  swk = (l31 & 7) << 2;      // dword-col XOR

        // ---- QK^T (swapped): S^T[k][q] = K . Q^T ----
        f32x16 S0 = (f32x16)0.0f, S1 = (f32x16)0.0f;
        #pragma unroll
        for (int ds = 0; ds < 8; ++ds) {
          int dc = (8 * ds + 4 * lg2) ^ swk;
          S0 = MFMA(ld_f16x8(kr0 + dc), qh[ds], S0);
          if (full) S1 = MFMA(ld_f16x8(kr1 + dc), qh[ds], S1);
        }

        // ---- causal mask (diagonal tile only) ----
        if (j == jmaxw) {
          #pragma unroll
          for (int r = 0; r < 16; ++r) {
            int crow = (r & 3) + 8 * (r >> 2) + 4 * lg2;
            if (crow > l31) { if (oddw) S1[r] = -1e30f; else S0[r] = -1e30f; }
          }
        }

        // ---- online softmax (base-2), T13 deferred rescale ----
        float tm = vmax16(S0);
        if (full) tm = fmaxf(tm, vmax16(S1));
        tm = fmaxf(tm, __shfl_xor(tm, 32));
        if (!__all(tm <= m2 + 8.0f)) {
          float m2n = fmaxf(m2, tm);
          float fac = exp2f(m2 - m2n);
          lsum *= fac;
          #pragma unroll
          for (int r = 0; r < 16; ++r) {
            int rq = (r & 3) + 8 * (r >> 2) + 4 * lg2;
            float fr = __shfl(fac, rq);
            O[0][r] *= fr; O[1][r] *= fr; O[2][r] *= fr; O[3][r] *= fr;
          }
          m2 = m2n;
        }
        u32 U[16];
        float ps = 0.0f;
        #pragma unroll
        for (int t = 0; t < 8; ++t) {
          float e0 = exp2f(S0[2 * t]     - m2);
          float e1 = exp2f(S0[2 * t + 1] - m2);
          U[t] = packh((_Float16)e0, (_Float16)e1);
          ps += e0 + e1;
        }
        if (full) {
          #pragma unroll
          for (int t = 0; t < 8; ++t) {
            float e0 = exp2f(S1[2 * t]     - m2);
            float e1 = exp2f(S1[2 * t + 1] - m2);
            U[8 + t] = packh((_Float16)e0, (_Float16)e1);
            ps += e0 + e1;
          }
        }
        ps += __shfl_xor(ps, 32);
        lsum += ps;

        // ---- PV: P fragments in-register via permlane32_swap ----
        #pragma unroll
        for (int ks = 0; ks < 4; ++ks) {
          if (ks >= 2 && !full) continue;
          u32 a0 = U[4 * ks + 0], a1 = U[4 * ks + 1];
          u32 b0 = U[4 * ks + 2], b1 = U[4 * ks + 3];
          asm("v_permlane32_swap_b32 %0, %1" : "+v"(a0), "+v"(b0));
          asm("v_permlane32_swap_b32 %0, %1" : "+v"(a1), "+v"(b1));
          u32x4 t4; t4.x = a0; t4.y = a1; t4.z = b0; t4.w = b1;
          f16x8 pa = __builtin_bit_cast(f16x8, t4);
          int dcv = (8 * ks + 4 * lg2) ^ swk;
          #pragma unroll
          for (int n = 0; n < 4; ++n) {
            O[n] = MFMA(pa, ld_f16x8(VB + (size_t)(32 * n + l31) * 32 + dcv), O[n]);
          }
        }
      }

      if (more) store_stage(s ^ 1);
      __syncthreads();
    }

    // ---------- epilogue ----------
    float inv = 1.0f / lsum;
    #pragma unroll
    for (int r = 0; r < 16; ++r) {
      int rq = (r & 3) + 8 * (r >> 2) + 4 * lg2;
      float fi = __shfl(inv, rq);
      float* orow = Og + (cbase + qs * 256 + w * 32 + rq) * 2048 + hoff + l31;
      orow[0]  = O[0][r] * fi;
      orow[32] = O[1][r] * fi;
      orow[64] = O[2][r] * fi;
      orow[96] = O[3][r] * fi;
    }
  }
}

// ================= fallback (R4/R6, passed) =================
#define KSTR 66
#define VSTR 34
#define KBUF (64 * KSTR)
#define STG  (KBUF + 128 * VSTR)

__global__ __launch_bounds__(512, 2)
void chunked_attn_fb(const float* __restrict__ Qg, const float* __restrict__ Kg,
                     const float* __restrict__ Vg, float* __restrict__ Og,
                     const float* __restrict__ tab) {
  __shared__ __align__(16) u32 lds[2 * STG];

  const int bx  = blockIdx.x;
  const int h   = bx & 15;
  const int p   = (bx >> 4) & 1;
  const int c   = (bx >> 5) & 3;
  const int b   = bx >> 7;
  const int tid = threadIdx.x;
  const int w   = tid >> 6;
  const int lane= tid & 63;
  const int l31 = lane & 31;
  const int lg2 = lane >> 5;

  const size_t cbase = (size_t)(b * Ll + c * 1024);
  const size_t hoff  = (size_t)h * 128;
  const int tb = c * 1024;

  f32x2 pk[8], pva[4], pvb[4];

  auto issue = [&](int j) {
    const float* kb_ = Kg + (cbase + (size_t)j * 64) * 2048 + hoff;
    const float* vb_ = Vg + (cbase + (size_t)j * 64) * 2048 + hoff;
    #pragma unroll
    for (int r = 0; r < 8; ++r)
      pk[r] = ld_f32x2(kb_ + (size_t)(8 * w + r) * 2048 + 2 * lane);
    #pragma unroll
    for (int rp = 0; rp < 4; ++rp) {
      const float* vr = vb_ + (size_t)(8 * w + 2 * rp) * 2048 + 2 * lane;
      pva[rp] = ld_f32x2(vr);
      pvb[rp] = ld_f32x2(vr + 2048);
    }
  };

  auto xform = [&](int j, int s) {
    u32* KB = lds + s * STG;
    u32* VB = KB + KBUF;
    const float* tbase = tab + (size_t)(tb + j * 64) * 128 + 4 * l31;
    f32x4 cs[8];
    #pragma unroll
    for (int r = 0; r < 8; ++r)
      cs[r] = ld_f32x4(tbase + (size_t)(8 * w + r) * 128);
    const float sgn = (lane < 32) ? -1.0f : 1.0f;
    #pragma unroll
    for (int r = 0; r < 8; ++r) {
      float a0 = pk[r].x, a1 = pk[r].y;
      float p0 = __shfl_xor(a0, 32), p1 = __shfl_xor(a1, 32);
      float o0 = a0 * cs[r].x + sgn * (p0 * cs[r].y);
      float o1 = a1 * cs[r].z + sgn * (p1 * cs[r].w);
      KB[(8 * w + r) * KSTR + lane] = packh((_Float16)o0, (_Float16)o1);
    }
    #pragma unroll
    for (int rp = 0; rp < 4; ++rp) {
      int kp = 4 * w + rp;
      VB[(2 * lane) * VSTR + kp]     = packh((_Float16)pva[rp].x, (_Float16)pvb[rp].x);
      VB[(2 * lane + 1) * VSTR + kp] = packh((_Float16)pva[rp].y, (_Float16)pvb[rp].y);
    }
  };

  #pragma unroll 1
  for (int sp = 0; sp < 2; ++sp) {
    const int qs = sp ? p : (3 - p);
    const int qrow = qs * 256 + w * 32 + l31;

    const float* qbase = Qg + (cbase + qrow) * 2048 + hoff;
    float xq[8][8];
    #pragma unroll
    for (int ds = 0; ds < 8; ++ds) {
      const float* ptr = qbase + ds * 16 + lg2 * 8;
      f32x4 v0 = ld_f32x4(ptr);
      f32x4 v1 = ld_f32x4(ptr + 4);
      xq[ds][0]=v0.x; xq[ds][1]=v0.y; xq[ds][2]=v0.z; xq[ds][3]=v0.w;
      xq[ds][4]=v1.x; xq[ds][5]=v1.y; xq[ds][6]=v1.z; xq[ds][7]=v1.w;
    }
    const float* trowq = tab + (size_t)(tb + qrow) * 128 + lg2 * 16;
    #pragma unroll
    for (int ds = 0; ds < 4; ++ds) {
      #pragma unroll
      for (int i2 = 0; i2 < 4; ++i2) {
        f32x4 cs = ld_f32x4(trowq + ds * 32 + i2 * 4);
        int i0 = 2 * i2;
        float a0 = xq[ds][i0],     b0 = xq[ds + 4][i0];
        xq[ds][i0]     = a0 * cs.x - b0 * cs.y;
        xq[ds + 4][i0] = b0 * cs.x + a0 * cs.y;
        float a1 = xq[ds][i0 + 1], b1 = xq[ds + 4][i0 + 1];
        xq[ds][i0 + 1]     = a1 * cs.z - b1 * cs.w;
        xq[ds + 4][i0 + 1] = b1 * cs.z + a1 * cs.w;
      }
    }
    f16x8 qh[8];
    #pragma unroll
    for (int ds = 0; ds < 8; ++ds)
      #pragma unroll
      for (int i = 0; i < 8; ++i)
        qh[ds][i] = (_Float16)(xq[ds][i] * QSCALE);

    f32x16 O[4];
    #pragma unroll
    for (int n = 0; n < 4; ++n) O[n] = (f32x16)0.0f;
    float m2 = -1e30f, lsum = 0.0f;
    const int  nt    = 4 * (qs + 1);
    const int  jmaxw = 4 * qs + (w >> 1);
    const bool oddw  = w & 1;

    issue(0);
    xform(0, 0);
    __syncthreads();

    for (int j = 0; j < nt; ++j) {
      const int s = j & 1;
      const bool more = (j + 1 < nt);
      if (more) issue(j + 1);

      if (j <= jmaxw) {
        const bool full = oddw || (j < jmaxw);
        const u32* KB = lds + s * STG;
        const u32* VB = KB + KBUF;
        const u32* kr0 = KB + (size_t)l31 * KSTR + lg2 * 4;
        const u32* kr1 = kr0 + (size_t)32 * KSTR;

        f32x16 S0 = (f32x16)0.0f, S1 = (f32x16)0.0f;
        #pragma unroll
        for (int ds = 0; ds < 8; ++ds) {
          S0 = MFMA(ld_frag(kr0 + ds * 8), qh[ds], S0);
          if (full) S1 = MFMA(ld_frag(kr1 + ds * 8), qh[ds], S1);
        }

        if (j == jmaxw) {
          #pragma unroll
          for (int r = 0; r < 16; ++r) {
            int crow = (r & 3) + 8 * (r >> 2) + 4 * lg2;
            if (crow > l31) { if (oddw) S1[r] = -1e30f; else S0[r] = -1e30f; }
          }
        }

        float tm = S0[0];
        #pragma unroll
        for (int r = 1; r < 16; ++r) tm = fmaxf(tm, S0[r]);
        if (full) {
          #pragma unroll
          for (int r = 0; r < 16; ++r) tm = fmaxf(tm, S1[r]);
        }
        tm = fmaxf(tm, __shfl_xor(tm, 32));
        if (!__all(tm <= m2 + 8.0f)) {
          float m2n = fmaxf(m2, tm);
          float fac = exp2f(m2 - m2n);
          lsum *= fac;
          #pragma unroll
          for (int r = 0; r < 16; ++r) {
            int rq = (r & 3) + 8 * (r >> 2) + 4 * lg2;
            float fr = __shfl(fac, rq);
            O[0][r] *= fr; O[1][r] *= fr; O[2][r] *= fr; O[3][r] *= fr;
          }
          m2 = m2n;
        }
        u32 U[16];
        float ps = 0.0f;
        #pragma unroll
        for (int t = 0; t < 8; ++t) {
          float e0 = exp2f(S0[2 * t]     - m2);
          float e1 = exp2f(S0[2 * t + 1] - m2);
          U[t] = packh((_Float16)e0, (_Float16)e1);
          ps += e0 + e1;
        }
        if (full) {
          #pragma unroll
          for (int t = 0; t < 8; ++t) {
            float e0 = exp2f(S1[2 * t]     - m2);
            float e1 = exp2f(S1[2 * t + 1] - m2);
            U[8 + t] = packh((_Float16)e0, (_Float16)e1);
            ps += e0 + e1;
          }
        }
        ps += __shfl_xor(ps, 32);
        lsum += ps;

        #pragma unroll
        for (int ks = 0; ks < 4; ++ks) {
          if (ks >= 2 && !full) continue;
          u32 a0 = U[4 * ks + 0], a1 = U[4 * ks + 1];
          u32 b0 = U[4 * ks + 2], b1 = U[4 * ks + 3];
          asm("v_permlane32_swap_b32 %0, %1" : "+v"(a0), "+v"(b0));
          asm("v_permlane32_swap_b32 %0, %1" : "+v"(a1), "+v"(b1));
          u32x4 t4; t4.x = a0; t4.y = a1; t4.z = b0; t4.w = b1;
          f16x8 pa = __builtin_bit_cast(f16x8, t4);
          #pragma unroll
          for (int n = 0; n < 4; ++n) {
            const u32* vp = VB + (size_t)(32 * n + l31) * VSTR + 8 * ks + 4 * lg2;
            O[n] = MFMA(pa, ld_frag(vp), O[n]);
          }
        }
      }

      if (more) xform(j + 1, s ^ 1);
      __syncthreads();
    }

    float inv = 1.0f / lsum;
    #pragma unroll
    for (int r = 0; r < 16; ++r) {
      int rq = (r & 3) + 8 * (r >> 2) + 4 * lg2;
      float fi = __shfl(inv, rq);
      float* orow = Og + (cbase + qs * 256 + w * 32 + rq) * 2048 + hoff + l31;
      orow[0]  = O[0][r] * fi;
      orow[32] = O[1][r] * fi;
      orow[64] = O[2][r] * fi;
      orow[96] = O[3][r] * fi;
    }
  }
}

extern "C" void kernel_launch(void* const* d_in, const int* in_sizes, int n_in,
                              void* d_out, int out_size, void* d_ws, size_t ws_size,
                              hipStream_t stream) {
  const float* q = (const float*)d_in[0];
  const float* k = (const float*)d_in[1];
  const float* v = (const float*)d_in[2];
  const int* start = (const int*)d_in[3];
  float* out = (float*)d_out;

  float* tab = (float*)d_ws;                          // 2 MB
  const size_t KH_OFFB = 2u * 1024 * 1024;            // 64 MB
  const size_t VT_OFFB = KH_OFFB + 64u * 1024 * 1024; // 64 MB
  const size_t NEED = VT_OFFB + 64u * 1024 * 1024;    // 130 MB total

  rope_table_k<<<dim3(1024), dim3(256), 0, stream>>>(start, tab);

  if (ws_size >= NEED) {
    u32* Kh = (u32*)((char*)d_ws + KH_OFFB);
    u32* VT = (u32*)((char*)d_ws + VT_OFFB);
    prep_merged_kernel<<<dim3(69632), dim3(256), 0, stream>>>(k, v, tab, Kh, VT);
    attn_f16_k<<<dim3(512), dim3(512), 0, stream>>>(q, Kh, VT, out, tab);
  } else {
    chunked_attn_fb<<<dim3(512), dim3(512), 0, stream>>>(q, k, v, out, tab);
  }
}

// Round 15
// 275.491 us; speedup vs baseline: 1.0027x; 1.0027x over previous
//
#include <hip/hip_runtime.h>

// ChunkedSelfAttention (RoPE + per-chunk causal SDPA), MI355X gfx950.
// R15 (final): dominant combination from session A/B matrix:
// packh P-pack (best margin, perf-neutral) + s_setprio around MFMA
// (R13/R14 A/B: -5us) + vmax16 tree (exact). Skeleton = R12 (best-known).
// Ladder: 497 -> 316 -> 273 -> 270 us.

typedef __attribute__((ext_vector_type(2)))  float     f32x2;
typedef __attribute__((ext_vector_type(4)))  float     f32x4;
typedef __attribute__((ext_vector_type(16))) float     f32x16;
typedef __attribute__((ext_vector_type(8)))  _Float16  f16x8;
typedef unsigned int   u32;
typedef unsigned short u16;
typedef __attribute__((ext_vector_type(4))) unsigned int u32x4;

#define MFMA(a, b, c) __builtin_amdgcn_mfma_f32_32x32x16_f16(a, b, c, 0, 0, 0)

constexpr int Ll = 4096;
constexpr float QSCALE = 0.08838834764831845f * 1.4426950408889634f; // 1/sqrt(128)*log2(e)

__device__ __forceinline__ f32x4 ld_f32x4(const void* p) { f32x4 v; __builtin_memcpy(&v, p, 16); return v; }
__device__ __forceinline__ f32x2 ld_f32x2(const void* p) { f32x2 v; __builtin_memcpy(&v, p, 8);  return v; }
__device__ __forceinline__ u32x4 ld_u32x4(const void* p) { u32x4 v; __builtin_memcpy(&v, p, 16); return v; }
__device__ __forceinline__ void  st_u32x4(void* p, u32x4 v) { __builtin_memcpy(p, &v, 16); }
__device__ __forceinline__ f16x8 ld_f16x8(const void* p) { f16x8 v; __builtin_memcpy(&v, p, 16); return v; }
__device__ __forceinline__ f16x8 ld_frag(const u32* dwp) {
  f16x8 v;
  __builtin_memcpy(&v, dwp, 8);
  __builtin_memcpy(((char*)&v) + 8, dwp + 2, 8);
  return v;
}
__device__ __forceinline__ u32 packh(_Float16 a, _Float16 b) {
  return (u32)__builtin_bit_cast(u16, a) | ((u32)__builtin_bit_cast(u16, b) << 16);
}

// ---- cos/sin table (verbatim R6) ----
__global__ void rope_table_k(const int* __restrict__ startp, float* __restrict__ tab) {
  int idx = blockIdx.x * 256 + threadIdx.x;
  int t = idx >> 6, hid = idx & 63;
  float a = (float)hid * (-0.14391156831212878f);
  float invf = expf(a);
  float ang = (float)(t + startp[0]) * invf;
  tab[2 * idx]     = cosf(ang);
  tab[2 * idx + 1] = sinf(ang);
}

// ---- merged prepass (verbatim R12) ----
__global__ __launch_bounds__(256)
void prep_merged_kernel(const float* __restrict__ Kg, const float* __restrict__ Vg,
                        const float* __restrict__ tab, u32* __restrict__ Kh,
                        u32* __restrict__ VT) {
  __shared__ __align__(16) u32 tile[4096];
  const int bx = blockIdx.x;
  if (bx < 65536) {
    const int R    = bx * 4 + (threadIdx.x >> 6);
    const int lane = threadIdx.x & 63;
    const int h  = R & 15;
    const int bt = R >> 4;
    const int b  = bt >> 12;
    const int t  = bt & 4095;
    const int c  = t >> 10;
    const int j  = (t >> 6) & 15;
    const int row = t & 63;
    const int GID = (b * 4 + c) * 16 + h;
    const int sw  = (row & 7) << 4;
    const int dc  = ((4 * lane) ^ sw) >> 1;
    f32x2 a = ld_f32x2(Kg + (size_t)R * 128 + dc);
    float p0 = __shfl_xor(a.x, 32);
    float p1 = __shfl_xor(a.y, 32);
    f32x4 cs = ld_f32x4(tab + (size_t)t * 128 + 2 * (dc & 63));
    const float sgn = (dc < 64) ? -1.0f : 1.0f;
    float o0 = a.x * cs.x + sgn * (p0 * cs.y);
    float o1 = a.y * cs.z + sgn * (p1 * cs.w);
    Kh[((size_t)(GID * 16 + j) * 64 + row) * 64 + lane] = packh((_Float16)o0, (_Float16)o1);
  } else {
    const int gj  = bx - 65536;
    const int GID = gj >> 4, j = gj & 15;
    const int h = GID & 15, c = (GID >> 4) & 3, b = GID >> 6;
    const int tid = threadIdx.x;
    const size_t rowbase = ((size_t)(b * 4096 + c * 1024 + j * 64)) * 16 + h;
    const int k  = tid >> 2;
    const int dq = tid & 3;
    u16* t16 = (u16*)tile;
    #pragma unroll
    for (int it = 0; it < 8; ++it) {
      int dv0 = dq * 4 + 16 * it;
      f32x4 v4 = ld_f32x4(Vg + (rowbase + (size_t)k * 16) * 128 + dv0);
      #pragma unroll
      for (int u = 0; u < 4; ++u) {
        int dv = dv0 + u;
        int ci = k ^ ((dv & 7) << 3);
        t16[dv * 64 + ci] = __builtin_bit_cast(u16, (_Float16)v4[u]);
      }
    }
    __syncthreads();
    const u32* tsrc = tile + 16 * tid;
    u32* dst = VT + (size_t)gj * 4096 + 16 * tid;
    #pragma unroll
    for (int u = 0; u < 4; ++u) st_u32x4(dst + 4 * u, ld_u32x4(tsrc + 4 * u));
  }
}

// ================= main attention (R6 skeleton, setprio, packh, vmax16) =================
__global__ __launch_bounds__(512, 2)
void attn_f16_k(const float* __restrict__ Qg, const u32* __restrict__ Kh,
                const u32* __restrict__ VT, float* __restrict__ Og,
                const float* __restrict__ tab) {
  __shared__ __align__(16) u32 lds[2 * 8192];   // 64 KB, double-buffered

  const int bx  = blockIdx.x;
  const int h   = bx & 15;
  const int p   = (bx >> 4) & 1;
  const int c   = (bx >> 5) & 3;
  const int b   = bx >> 7;
  const int tid = threadIdx.x;
  const int w   = tid >> 6;
  const int lane= tid & 63;
  const int l31 = lane & 31;
  const int lg2 = lane >> 5;

  const size_t cbase = (size_t)(b * Ll + c * 1024);
  const size_t hoff  = (size_t)h * 128;
  const int tb  = c * 1024;
  const int GID = (b * 4 + c) * 16 + h;
  const u32* khg = Kh + (size_t)GID * 16 * 4096;
  const u32* vtg = VT + (size_t)GID * 16 * 4096;

  u32x4 stg[4];
  auto issue = [&](int j) {
    #pragma unroll
    for (int i = 0; i < 4; ++i) {
      int ch = w + 8 * i;                // 32 chunks of 1 KB: 0..15 K, 16..31 VT
      const u32* src = (ch < 16) ? (khg + (size_t)j * 4096 + ch * 256 + 4 * lane)
                                 : (vtg + (size_t)j * 4096 + (ch - 16) * 256 + 4 * lane);
      stg[i] = ld_u32x4(src);
    }
  };
  auto store_stage = [&](int s) {
    u32* dst0 = lds + (size_t)s * 8192;
    #pragma unroll
    for (int i = 0; i < 4; ++i) {
      int ch = w + 8 * i;
      st_u32x4(dst0 + ch * 256 + 4 * lane, stg[i]);
    }
  };

  auto vmax16 = [](const f32x16& S) {
    float a0 = fmaxf(S[0], S[1]),   a1 = fmaxf(S[2], S[3]);
    float a2 = fmaxf(S[4], S[5]),   a3 = fmaxf(S[6], S[7]);
    float a4 = fmaxf(S[8], S[9]),   a5 = fmaxf(S[10], S[11]);
    float a6 = fmaxf(S[12], S[13]), a7 = fmaxf(S[14], S[15]);
    float b0 = fmaxf(a0, a1), b1 = fmaxf(a2, a3);
    float b2 = fmaxf(a4, a5), b3 = fmaxf(a6, a7);
    return fmaxf(fmaxf(b0, b1), fmaxf(b2, b3));
  };

  #pragma unroll 1
  for (int sp = 0; sp < 2; ++sp) {
    const int qs = sp ? p : (3 - p);            // heavy strip first
    const int qrow = qs * 256 + w * 32 + l31;

    // ---------- Q prologue: load f32, rope, scale, f16 ----------
    const float* qbase = Qg + (cbase + qrow) * 2048 + hoff;
    float xq[8][8];
    #pragma unroll
    for (int ds = 0; ds < 8; ++ds) {
      const float* ptr = qbase + ds * 16 + lg2 * 8;
      f32x4 v0 = ld_f32x4(ptr);
      f32x4 v1 = ld_f32x4(ptr + 4);
      xq[ds][0]=v0.x; xq[ds][1]=v0.y; xq[ds][2]=v0.z; xq[ds][3]=v0.w;
      xq[ds][4]=v1.x; xq[ds][5]=v1.y; xq[ds][6]=v1.z; xq[ds][7]=v1.w;
    }
    const float* trowq = tab + (size_t)(tb + qrow) * 128 + lg2 * 16;
    #pragma unroll
    for (int ds = 0; ds < 4; ++ds) {
      #pragma unroll
      for (int i2 = 0; i2 < 4; ++i2) {
        f32x4 cs = ld_f32x4(trowq + ds * 32 + i2 * 4);
        int i0 = 2 * i2;
        float a0 = xq[ds][i0],     b0 = xq[ds + 4][i0];
        xq[ds][i0]     = a0 * cs.x - b0 * cs.y;
        xq[ds + 4][i0] = b0 * cs.x + a0 * cs.y;
        float a1 = xq[ds][i0 + 1], b1 = xq[ds + 4][i0 + 1];
        xq[ds][i0 + 1]     = a1 * cs.z - b1 * cs.w;
        xq[ds + 4][i0 + 1] = b1 * cs.z + a1 * cs.w;
      }
    }
    f16x8 qh[8];
    #pragma unroll
    for (int ds = 0; ds < 8; ++ds)
      #pragma unroll
      for (int i = 0; i < 8; ++i)
        qh[ds][i] = (_Float16)(xq[ds][i] * QSCALE);

    // ---------- state ----------
    f32x16 O[4];
    #pragma unroll
    for (int n = 0; n < 4; ++n) O[n] = (f32x16)0.0f;
    float m2 = -1e30f, lsum = 0.0f;
    const int  nt    = 4 * (qs + 1);
    const int  jmaxw = 4 * qs + (w >> 1);
    const bool oddw  = w & 1;

    issue(0);
    store_stage(0);
    __syncthreads();

    for (int j = 0; j < nt; ++j) {
      const int s = j & 1;
      const bool more = (j + 1 < nt);
      if (more) issue(j + 1);          // global loads fly under compute

      if (j <= jmaxw) {
        const bool full = oddw || (j < jmaxw);
        const u32* KB = lds + (size_t)s * 8192;
        const u32* VB = KB + 4096;
        const u32* kr0 = KB + (size_t)l31 * 64;
        const u32* kr1 = kr0 + 32 * 64;
        const int  swk = (l31 & 7) << 2;      // dword-col XOR

        // ---- QK^T (swapped): S^T[k][q] = K . Q^T ----
        f32x16 S0 = (f32x16)0.0f, S1 = (f32x16)0.0f;
        __builtin_amdgcn_s_setprio(1);
        #pragma unroll
        for (int ds = 0; ds < 8; ++ds) {
          int dc = (8 * ds + 4 * lg2) ^ swk;
          S0 = MFMA(ld_f16x8(kr0 + dc), qh[ds], S0);
          if (full) S1 = MFMA(ld_f16x8(kr1 + dc), qh[ds], S1);
        }
        __builtin_amdgcn_s_setprio(0);

        // ---- causal mask (diagonal tile only) ----
        if (j == jmaxw) {
          #pragma unroll
          for (int r = 0; r < 16; ++r) {
            int crow = (r & 3) + 8 * (r >> 2) + 4 * lg2;
            if (crow > l31) { if (oddw) S1[r] = -1e30f; else S0[r] = -1e30f; }
          }
        }

        // ---- online softmax (base-2), T13 deferred rescale ----
        float tm = vmax16(S0);
        if (full) tm = fmaxf(tm, vmax16(S1));
        tm = fmaxf(tm, __shfl_xor(tm, 32));
        if (!__all(tm <= m2 + 8.0f)) {
          float m2n = fmaxf(m2, tm);
          float fac = exp2f(m2 - m2n);
          lsum *= fac;
          #pragma unroll
          for (int r = 0; r < 16; ++r) {
            int rq = (r & 3) + 8 * (r >> 2) + 4 * lg2;
            float fr = __shfl(fac, rq);
            O[0][r] *= fr; O[1][r] *= fr; O[2][r] *= fr; O[3][r] *= fr;
          }
          m2 = m2n;
        }
        u32 U[16];
        float ps = 0.0f;
        #pragma unroll
        for (int t = 0; t < 8; ++t) {
          float e0 = exp2f(S0[2 * t]     - m2);
          float e1 = exp2f(S0[2 * t + 1] - m2);
          U[t] = packh((_Float16)e0, (_Float16)e1);
          ps += e0 + e1;
        }
        if (full) {
          #pragma unroll
          for (int t = 0; t < 8; ++t) {
            float e0 = exp2f(S1[2 * t]     - m2);
            float e1 = exp2f(S1[2 * t + 1] - m2);
            U[8 + t] = packh((_Float16)e0, (_Float16)e1);
            ps += e0 + e1;
          }
        }
        ps += __shfl_xor(ps, 32);
        lsum += ps;

        // ---- PV: P fragments in-register via permlane32_swap ----
        __builtin_amdgcn_s_setprio(1);
        #pragma unroll
        for (int ks = 0; ks < 4; ++ks) {
          if (ks >= 2 && !full) continue;
          u32 a0 = U[4 * ks + 0], a1 = U[4 * ks + 1];
          u32 b0 = U[4 * ks + 2], b1 = U[4 * ks + 3];
          asm("v_permlane32_swap_b32 %0, %1" : "+v"(a0), "+v"(b0));
          asm("v_permlane32_swap_b32 %0, %1" : "+v"(a1), "+v"(b1));
          u32x4 t4; t4.x = a0; t4.y = a1; t4.z = b0; t4.w = b1;
          f16x8 pa = __builtin_bit_cast(f16x8, t4);
          int dcv = (8 * ks + 4 * lg2) ^ swk;
          #pragma unroll
          for (int n = 0; n < 4; ++n) {
            O[n] = MFMA(pa, ld_f16x8(VB + (size_t)(32 * n + l31) * 32 + dcv), O[n]);
          }
        }
        __builtin_amdgcn_s_setprio(0);
      }

      if (more) store_stage(s ^ 1);
      __syncthreads();
    }

    // ---------- epilogue ----------
    float inv = 1.0f / lsum;
    #pragma unroll
    for (int r = 0; r < 16; ++r) {
      int rq = (r & 3) + 8 * (r >> 2) + 4 * lg2;
      float fi = __shfl(inv, rq);
      float* orow = Og + (cbase + qs * 256 + w * 32 + rq) * 2048 + hoff + l31;
      orow[0]  = O[0][r] * fi;
      orow[32] = O[1][r] * fi;
      orow[64] = O[2][r] * fi;
      orow[96] = O[3][r] * fi;
    }
  }
}

// ================= fallback (R4/R6, passed) =================
#define KSTR 66
#define VSTR 34
#define KBUF (64 * KSTR)
#define STG  (KBUF + 128 * VSTR)

__global__ __launch_bounds__(512, 2)
void chunked_attn_fb(const float* __restrict__ Qg, const float* __restrict__ Kg,
                     const float* __restrict__ Vg, float* __restrict__ Og,
                     const float* __restrict__ tab) {
  __shared__ __align__(16) u32 lds[2 * STG];

  const int bx  = blockIdx.x;
  const int h   = bx & 15;
  const int p   = (bx >> 4) & 1;
  const int c   = (bx >> 5) & 3;
  const int b   = bx >> 7;
  const int tid = threadIdx.x;
  const int w   = tid >> 6;
  const int lane= tid & 63;
  const int l31 = lane & 31;
  const int lg2 = lane >> 5;

  const size_t cbase = (size_t)(b * Ll + c * 1024);
  const size_t hoff  = (size_t)h * 128;
  const int tb = c * 1024;

  f32x2 pk[8], pva[4], pvb[4];

  auto issue = [&](int j) {
    const float* kb_ = Kg + (cbase + (size_t)j * 64) * 2048 + hoff;
    const float* vb_ = Vg + (cbase + (size_t)j * 64) * 2048 + hoff;
    #pragma unroll
    for (int r = 0; r < 8; ++r)
      pk[r] = ld_f32x2(kb_ + (size_t)(8 * w + r) * 2048 + 2 * lane);
    #pragma unroll
    for (int rp = 0; rp < 4; ++rp) {
      const float* vr = vb_ + (size_t)(8 * w + 2 * rp) * 2048 + 2 * lane;
      pva[rp] = ld_f32x2(vr);
      pvb[rp] = ld_f32x2(vr + 2048);
    }
  };

  auto xform = [&](int j, int s) {
    u32* KB = lds + s * STG;
    u32* VB = KB + KBUF;
    const float* tbase = tab + (size_t)(tb + j * 64) * 128 + 4 * l31;
    f32x4 cs[8];
    #pragma unroll
    for (int r = 0; r < 8; ++r)
      cs[r] = ld_f32x4(tbase + (size_t)(8 * w + r) * 128);
    const float sgn = (lane < 32) ? -1.0f : 1.0f;
    #pragma unroll
    for (int r = 0; r < 8; ++r) {
      float a0 = pk[r].x, a1 = pk[r].y;
      float p0 = __shfl_xor(a0, 32), p1 = __shfl_xor(a1, 32);
      float o0 = a0 * cs[r].x + sgn * (p0 * cs[r].y);
      float o1 = a1 * cs[r].z + sgn * (p1 * cs[r].w);
      KB[(8 * w + r) * KSTR + lane] = packh((_Float16)o0, (_Float16)o1);
    }
    #pragma unroll
    for (int rp = 0; rp < 4; ++rp) {
      int kp = 4 * w + rp;
      VB[(2 * lane) * VSTR + kp]     = packh((_Float16)pva[rp].x, (_Float16)pvb[rp].x);
      VB[(2 * lane + 1) * VSTR + kp] = packh((_Float16)pva[rp].y, (_Float16)pvb[rp].y);
    }
  };

  #pragma unroll 1
  for (int sp = 0; sp < 2; ++sp) {
    const int qs = sp ? p : (3 - p);
    const int qrow = qs * 256 + w * 32 + l31;

    const float* qbase = Qg + (cbase + qrow) * 2048 + hoff;
    float xq[8][8];
    #pragma unroll
    for (int ds = 0; ds < 8; ++ds) {
      const float* ptr = qbase + ds * 16 + lg2 * 8;
      f32x4 v0 = ld_f32x4(ptr);
      f32x4 v1 = ld_f32x4(ptr + 4);
      xq[ds][0]=v0.x; xq[ds][1]=v0.y; xq[ds][2]=v0.z; xq[ds][3]=v0.w;
      xq[ds][4]=v1.x; xq[ds][5]=v1.y; xq[ds][6]=v1.z; xq[ds][7]=v1.w;
    }
    const float* trowq = tab + (size_t)(tb + qrow) * 128 + lg2 * 16;
    #pragma unroll
    for (int ds = 0; ds < 4; ++ds) {
      #pragma unroll
      for (int i2 = 0; i2 < 4; ++i2) {
        f32x4 cs = ld_f32x4(trowq + ds * 32 + i2 * 4);
        int i0 = 2 * i2;
        float a0 = xq[ds][i0],     b0 = xq[ds + 4][i0];
        xq[ds][i0]     = a0 * cs.x - b0 * cs.y;
        xq[ds + 4][i0] = b0 * cs.x + a0 * cs.y;
        float a1 = xq[ds][i0 + 1], b1 = xq[ds + 4][i0 + 1];
        xq[ds][i0 + 1]     = a1 * cs.z - b1 * cs.w;
        xq[ds + 4][i0 + 1] = b1 * cs.z + a1 * cs.w;
      }
    }
    f16x8 qh[8];
    #pragma unroll
    for (int ds = 0; ds < 8; ++ds)
      #pragma unroll
      for (int i = 0; i < 8; ++i)
        qh[ds][i] = (_Float16)(xq[ds][i] * QSCALE);

    f32x16 O[4];
    #pragma unroll
    for (int n = 0; n < 4; ++n) O[n] = (f32x16)0.0f;
    float m2 = -1e30f, lsum = 0.0f;
    const int  nt    = 4 * (qs + 1);
    const int  jmaxw = 4 * qs + (w >> 1);
    const bool oddw  = w & 1;

    issue(0);
    xform(0, 0);
    __syncthreads();

    for (int j = 0; j < nt; ++j) {
      const int s = j & 1;
      const bool more = (j + 1 < nt);
      if (more) issue(j + 1);

      if (j <= jmaxw) {
        const bool full = oddw || (j < jmaxw);
        const u32* KB = lds + s * STG;
        const u32* VB = KB + KBUF;
        const u32* kr0 = KB + (size_t)l31 * KSTR + lg2 * 4;
        const u32* kr1 = kr0 + (size_t)32 * KSTR;

        f32x16 S0 = (f32x16)0.0f, S1 = (f32x16)0.0f;
        __builtin_amdgcn_s_setprio(1);
        #pragma unroll
        for (int ds = 0; ds < 8; ++ds) {
          S0 = MFMA(ld_frag(kr0 + ds * 8), qh[ds], S0);
          if (full) S1 = MFMA(ld_frag(kr1 + ds * 8), qh[ds], S1);
        }
        __builtin_amdgcn_s_setprio(0);

        if (j == jmaxw) {
          #pragma unroll
          for (int r = 0; r < 16; ++r) {
            int crow = (r & 3) + 8 * (r >> 2) + 4 * lg2;
            if (crow > l31) { if (oddw) S1[r] = -1e30f; else S0[r] = -1e30f; }
          }
        }

        float tm = S0[0];
        #pragma unroll
        for (int r = 1; r < 16; ++r) tm = fmaxf(tm, S0[r]);
        if (full) {
          #pragma unroll
          for (int r = 0; r < 16; ++r) tm = fmaxf(tm, S1[r]);
        }
        tm = fmaxf(tm, __shfl_xor(tm, 32));
        if (!__all(tm <= m2 + 8.0f)) {
          float m2n = fmaxf(m2, tm);
          float fac = exp2f(m2 - m2n);
          lsum *= fac;
          #pragma unroll
          for (int r = 0; r < 16; ++r) {
            int rq = (r & 3) + 8 * (r >> 2) + 4 * lg2;
            float fr = __shfl(fac, rq);
            O[0][r] *= fr; O[1][r] *= fr; O[2][r] *= fr; O[3][r] *= fr;
          }
          m2 = m2n;
        }
        u32 U[16];
        float ps = 0.0f;
        #pragma unroll
        for (int t = 0; t < 8; ++t) {
          float e0 = exp2f(S0[2 * t]     - m2);
          float e1 = exp2f(S0[2 * t + 1] - m2);
          U[t] = packh((_Float16)e0, (_Float16)e1);
          ps += e0 + e1;
        }
        if (full) {
          #pragma unroll
          for (int t = 0; t < 8; ++t) {
            float e0 = exp2f(S1[2 * t]     - m2);
            float e1 = exp2f(S1[2 * t + 1] - m2);
            U[8 + t] = packh((_Float16)e0, (_Float16)e1);
            ps += e0 + e1;
          }
        }
        ps += __shfl_xor(ps, 32);
        lsum += ps;

        __builtin_amdgcn_s_setprio(1);
        #pragma unroll
        for (int ks = 0; ks < 4; ++ks) {
          if (ks >= 2 && !full) continue;
          u32 a0 = U[4 * ks + 0], a1 = U[4 * ks + 1];
          u32 b0 = U[4 * ks + 2], b1 = U[4 * ks + 3];
          asm("v_permlane32_swap_b32 %0, %1" : "+v"(a0), "+v"(b0));
          asm("v_permlane32_swap_b32 %0, %1" : "+v"(a1), "+v"(b1));
          u32x4 t4; t4.x = a0; t4.y = a1; t4.z = b0; t4.w = b1;
          f16x8 pa = __builtin_bit_cast(f16x8, t4);
          #pragma unroll
          for (int n = 0; n < 4; ++n) {
            const u32* vp = VB + (size_t)(32 * n + l31) * VSTR + 8 * ks + 4 * lg2;
            O[n] = MFMA(pa, ld_frag(vp), O[n]);
          }
        }
        __builtin_amdgcn_s_setprio(0);
      }

      if (more) xform(j + 1, s ^ 1);
      __syncthreads();
    }

    float inv = 1.0f / lsum;
    #pragma unroll
    for (int r = 0; r < 16; ++r) {
      int rq = (r & 3) + 8 * (r >> 2) + 4 * lg2;
      float fi = __shfl(inv, rq);
      float* orow = Og + (cbase + qs * 256 + w * 32 + rq) * 2048 + hoff + l31;
      orow[0]  = O[0][r] * fi;
      orow[32] = O[1][r] * fi;
      orow[64] = O[2][r] * fi;
      orow[96] = O[3][r] * fi;
    }
  }
}

extern "C" void kernel_launch(void* const* d_in, const int* in_sizes, int n_in,
                              void* d_out, int out_size, void* d_ws, size_t ws_size,
                              hipStream_t stream) {
  const float* q = (const float*)d_in[0];
  const float* k = (const float*)d_in[1];
  const float* v = (const float*)d_in[2];
  const int* start = (const int*)d_in[3];
  float* out = (float*)d_out;

  float* tab = (float*)d_ws;                          // 2 MB
  const size_t KH_OFFB = 2u * 1024 * 1024;            // 64 MB
  const size_t VT_OFFB = KH_OFFB + 64u * 1024 * 1024; // 64 MB
  const size_t NEED = VT_OFFB + 64u * 1024 * 1024;    // 130 MB total

  rope_table_k<<<dim3(1024), dim3(256), 0, stream>>>(start, tab);

  if (ws_size >= NEED) {
    u32* Kh = (u32*)((char*)d_ws + KH_OFFB);
    u32* VT = (u32*)((char*)d_ws + VT_OFFB);
    prep_merged_kernel<<<dim3(69632), dim3(256), 0, stream>>>(k, v, tab, Kh, VT);
    attn_f16_k<<<dim3(512), dim3(512), 0, stream>>>(q, Kh, VT, out, tab);
  } else {
    chunked_attn_fb<<<dim3(512), dim3(512), 0, stream>>>(q, k, v, out, tab);
  }
}

// Round 16
// 271.616 us; speedup vs baseline: 1.0170x; 1.0143x over previous
//
#include <hip/hip_runtime.h>

// ChunkedSelfAttention (RoPE + per-chunk causal SDPA), MI355X gfx950.
// R16 (final submission): R12 verbatim — the session's best-measured config
// (270.1 us, absmax 0.0273 = largest correctness margin). R13-R15 A/Bs
// established run noise ~±3us total; all variants statistically tied, so
// we bank the best-measured one. Structure: merged f16 prepass (rope-K +
// V^T, pre-swizzled LDS-ready layout in d_ws) + 8-wave flash attention
// (64-key tiles, double-buffered reg staging, swapped-QK in-register
// softmax, permlane32 P fragments, diagonal half-skip, deferred rescale).

typedef __attribute__((ext_vector_type(2)))  float     f32x2;
typedef __attribute__((ext_vector_type(4)))  float     f32x4;
typedef __attribute__((ext_vector_type(16))) float     f32x16;
typedef __attribute__((ext_vector_type(8)))  _Float16  f16x8;
typedef unsigned int   u32;
typedef unsigned short u16;
typedef __attribute__((ext_vector_type(4))) unsigned int u32x4;

#define MFMA(a, b, c) __builtin_amdgcn_mfma_f32_32x32x16_f16(a, b, c, 0, 0, 0)

constexpr int Ll = 4096;
constexpr float QSCALE = 0.08838834764831845f * 1.4426950408889634f; // 1/sqrt(128)*log2(e)

__device__ __forceinline__ f32x4 ld_f32x4(const void* p) { f32x4 v; __builtin_memcpy(&v, p, 16); return v; }
__device__ __forceinline__ f32x2 ld_f32x2(const void* p) { f32x2 v; __builtin_memcpy(&v, p, 8);  return v; }
__device__ __forceinline__ u32x4 ld_u32x4(const void* p) { u32x4 v; __builtin_memcpy(&v, p, 16); return v; }
__device__ __forceinline__ void  st_u32x4(void* p, u32x4 v) { __builtin_memcpy(p, &v, 16); }
__device__ __forceinline__ f16x8 ld_f16x8(const void* p) { f16x8 v; __builtin_memcpy(&v, p, 16); return v; }
__device__ __forceinline__ f16x8 ld_frag(const u32* dwp) {
  f16x8 v;
  __builtin_memcpy(&v, dwp, 8);
  __builtin_memcpy(((char*)&v) + 8, dwp + 2, 8);
  return v;
}
__device__ __forceinline__ u32 packh(_Float16 a, _Float16 b) {
  return (u32)__builtin_bit_cast(u16, a) | ((u32)__builtin_bit_cast(u16, b) << 16);
}

// ---- cos/sin table: tab[t*128 + 2*hid] = {cos, sin}, ang = (t+start)*inv_freq ----
__global__ void rope_table_k(const int* __restrict__ startp, float* __restrict__ tab) {
  int idx = blockIdx.x * 256 + threadIdx.x;
  int t = idx >> 6, hid = idx & 63;
  float a = (float)hid * (-0.14391156831212878f);
  float invf = expf(a);
  float ang = (float)(t + startp[0]) * invf;
  tab[2 * idx]     = cosf(ang);
  tab[2 * idx + 1] = sinf(ang);
}

// ---- merged prepass: blocks [0,65536) = K (roped f16, swizzled);
//      blocks [65536,69632) = V^T f16 swizzled. ----
__global__ __launch_bounds__(256)
void prep_merged_kernel(const float* __restrict__ Kg, const float* __restrict__ Vg,
                        const float* __restrict__ tab, u32* __restrict__ Kh,
                        u32* __restrict__ VT) {
  __shared__ __align__(16) u32 tile[4096];
  const int bx = blockIdx.x;
  if (bx < 65536) {
    const int R    = bx * 4 + (threadIdx.x >> 6);
    const int lane = threadIdx.x & 63;
    const int h  = R & 15;
    const int bt = R >> 4;
    const int b  = bt >> 12;
    const int t  = bt & 4095;
    const int c  = t >> 10;
    const int j  = (t >> 6) & 15;
    const int row = t & 63;
    const int GID = (b * 4 + c) * 16 + h;
    const int sw  = (row & 7) << 4;
    const int dc  = ((4 * lane) ^ sw) >> 1;
    f32x2 a = ld_f32x2(Kg + (size_t)R * 128 + dc);
    float p0 = __shfl_xor(a.x, 32);
    float p1 = __shfl_xor(a.y, 32);
    f32x4 cs = ld_f32x4(tab + (size_t)t * 128 + 2 * (dc & 63));
    const float sgn = (dc < 64) ? -1.0f : 1.0f;
    float o0 = a.x * cs.x + sgn * (p0 * cs.y);
    float o1 = a.y * cs.z + sgn * (p1 * cs.w);
    Kh[((size_t)(GID * 16 + j) * 64 + row) * 64 + lane] = packh((_Float16)o0, (_Float16)o1);
  } else {
    const int gj  = bx - 65536;
    const int GID = gj >> 4, j = gj & 15;
    const int h = GID & 15, c = (GID >> 4) & 3, b = GID >> 6;
    const int tid = threadIdx.x;
    const size_t rowbase = ((size_t)(b * 4096 + c * 1024 + j * 64)) * 16 + h;
    const int k  = tid >> 2;
    const int dq = tid & 3;
    u16* t16 = (u16*)tile;
    #pragma unroll
    for (int it = 0; it < 8; ++it) {
      int dv0 = dq * 4 + 16 * it;
      f32x4 v4 = ld_f32x4(Vg + (rowbase + (size_t)k * 16) * 128 + dv0);
      #pragma unroll
      for (int u = 0; u < 4; ++u) {
        int dv = dv0 + u;
        int ci = k ^ ((dv & 7) << 3);
        t16[dv * 64 + ci] = __builtin_bit_cast(u16, (_Float16)v4[u]);
      }
    }
    __syncthreads();
    const u32* tsrc = tile + 16 * tid;
    u32* dst = VT + (size_t)gj * 4096 + 16 * tid;
    #pragma unroll
    for (int u = 0; u < 4; ++u) st_u32x4(dst + 4 * u, ld_u32x4(tsrc + 4 * u));
  }
}

// ================= main attention (R6 skeleton: best-measured) =================
__global__ __launch_bounds__(512, 2)
void attn_f16_k(const float* __restrict__ Qg, const u32* __restrict__ Kh,
                const u32* __restrict__ VT, float* __restrict__ Og,
                const float* __restrict__ tab) {
  __shared__ __align__(16) u32 lds[2 * 8192];   // 64 KB, double-buffered

  const int bx  = blockIdx.x;
  const int h   = bx & 15;
  const int p   = (bx >> 4) & 1;
  const int c   = (bx >> 5) & 3;
  const int b   = bx >> 7;
  const int tid = threadIdx.x;
  const int w   = tid >> 6;
  const int lane= tid & 63;
  const int l31 = lane & 31;
  const int lg2 = lane >> 5;

  const size_t cbase = (size_t)(b * Ll + c * 1024);
  const size_t hoff  = (size_t)h * 128;
  const int tb  = c * 1024;
  const int GID = (b * 4 + c) * 16 + h;
  const u32* khg = Kh + (size_t)GID * 16 * 4096;
  const u32* vtg = VT + (size_t)GID * 16 * 4096;

  u32x4 stg[4];
  auto issue = [&](int j) {
    #pragma unroll
    for (int i = 0; i < 4; ++i) {
      int ch = w + 8 * i;                // 32 chunks of 1 KB: 0..15 K, 16..31 VT
      const u32* src = (ch < 16) ? (khg + (size_t)j * 4096 + ch * 256 + 4 * lane)
                                 : (vtg + (size_t)j * 4096 + (ch - 16) * 256 + 4 * lane);
      stg[i] = ld_u32x4(src);
    }
  };
  auto store_stage = [&](int s) {
    u32* dst0 = lds + (size_t)s * 8192;
    #pragma unroll
    for (int i = 0; i < 4; ++i) {
      int ch = w + 8 * i;
      st_u32x4(dst0 + ch * 256 + 4 * lane, stg[i]);
    }
  };

  #pragma unroll 1
  for (int sp = 0; sp < 2; ++sp) {
    const int qs = sp ? p : (3 - p);            // heavy strip first
    const int qrow = qs * 256 + w * 32 + l31;

    // ---------- Q prologue: load f32, rope, scale, f16 ----------
    const float* qbase = Qg + (cbase + qrow) * 2048 + hoff;
    float xq[8][8];
    #pragma unroll
    for (int ds = 0; ds < 8; ++ds) {
      const float* ptr = qbase + ds * 16 + lg2 * 8;
      f32x4 v0 = ld_f32x4(ptr);
      f32x4 v1 = ld_f32x4(ptr + 4);
      xq[ds][0]=v0.x; xq[ds][1]=v0.y; xq[ds][2]=v0.z; xq[ds][3]=v0.w;
      xq[ds][4]=v1.x; xq[ds][5]=v1.y; xq[ds][6]=v1.z; xq[ds][7]=v1.w;
    }
    const float* trowq = tab + (size_t)(tb + qrow) * 128 + lg2 * 16;
    #pragma unroll
    for (int ds = 0; ds < 4; ++ds) {
      #pragma unroll
      for (int i2 = 0; i2 < 4; ++i2) {
        f32x4 cs = ld_f32x4(trowq + ds * 32 + i2 * 4);
        int i0 = 2 * i2;
        float a0 = xq[ds][i0],     b0 = xq[ds + 4][i0];
        xq[ds][i0]     = a0 * cs.x - b0 * cs.y;
        xq[ds + 4][i0] = b0 * cs.x + a0 * cs.y;
        float a1 = xq[ds][i0 + 1], b1 = xq[ds + 4][i0 + 1];
        xq[ds][i0 + 1]     = a1 * cs.z - b1 * cs.w;
        xq[ds + 4][i0 + 1] = b1 * cs.z + a1 * cs.w;
      }
    }
    f16x8 qh[8];
    #pragma unroll
    for (int ds = 0; ds < 8; ++ds)
      #pragma unroll
      for (int i = 0; i < 8; ++i)
        qh[ds][i] = (_Float16)(xq[ds][i] * QSCALE);

    // ---------- state ----------
    f32x16 O[4];
    #pragma unroll
    for (int n = 0; n < 4; ++n) O[n] = (f32x16)0.0f;
    float m2 = -1e30f, lsum = 0.0f;
    const int  nt    = 4 * (qs + 1);
    const int  jmaxw = 4 * qs + (w >> 1);
    const bool oddw  = w & 1;

    issue(0);
    store_stage(0);
    __syncthreads();

    for (int j = 0; j < nt; ++j) {
      const int s = j & 1;
      const bool more = (j + 1 < nt);
      if (more) issue(j + 1);          // global loads fly under compute

      if (j <= jmaxw) {
        const bool full = oddw || (j < jmaxw);
        const u32* KB = lds + (size_t)s * 8192;
        const u32* VB = KB + 4096;
        const u32* kr0 = KB + (size_t)l31 * 64;
        const u32* kr1 = kr0 + 32 * 64;
        const int  swk = (l31 & 7) << 2;      // dword-col XOR

        // ---- QK^T (swapped): S^T[k][q] = K . Q^T ----
        f32x16 S0 = (f32x16)0.0f, S1 = (f32x16)0.0f;
        __builtin_amdgcn_s_setprio(1);
        #pragma unroll
        for (int ds = 0; ds < 8; ++ds) {
          int dc = (8 * ds + 4 * lg2) ^ swk;
          S0 = MFMA(ld_f16x8(kr0 + dc), qh[ds], S0);
          if (full) S1 = MFMA(ld_f16x8(kr1 + dc), qh[ds], S1);
        }
        __builtin_amdgcn_s_setprio(0);

        // ---- causal mask (diagonal tile only) ----
        if (j == jmaxw) {
          #pragma unroll
          for (int r = 0; r < 16; ++r) {
            int crow = (r & 3) + 8 * (r >> 2) + 4 * lg2;
            if (crow > l31) { if (oddw) S1[r] = -1e30f; else S0[r] = -1e30f; }
          }
        }

        // ---- online softmax (base-2), T13 deferred rescale ----
        float tm = S0[0];
        #pragma unroll
        for (int r = 1; r < 16; ++r) tm = fmaxf(tm, S0[r]);
        if (full) {
          #pragma unroll
          for (int r = 0; r < 16; ++r) tm = fmaxf(tm, S1[r]);
        }
        tm = fmaxf(tm, __shfl_xor(tm, 32));
        if (!__all(tm <= m2 + 8.0f)) {
          float m2n = fmaxf(m2, tm);
          float fac = exp2f(m2 - m2n);
          lsum *= fac;
          #pragma unroll
          for (int r = 0; r < 16; ++r) {
            int rq = (r & 3) + 8 * (r >> 2) + 4 * lg2;
            float fr = __shfl(fac, rq);
            O[0][r] *= fr; O[1][r] *= fr; O[2][r] *= fr; O[3][r] *= fr;
          }
          m2 = m2n;
        }
        u32 U[16];
        float ps = 0.0f;
        #pragma unroll
        for (int t = 0; t < 8; ++t) {
          float e0 = exp2f(S0[2 * t]     - m2);
          float e1 = exp2f(S0[2 * t + 1] - m2);
          U[t] = packh((_Float16)e0, (_Float16)e1);
          ps += e0 + e1;
        }
        if (full) {
          #pragma unroll
          for (int t = 0; t < 8; ++t) {
            float e0 = exp2f(S1[2 * t]     - m2);
            float e1 = exp2f(S1[2 * t + 1] - m2);
            U[8 + t] = packh((_Float16)e0, (_Float16)e1);
            ps += e0 + e1;
          }
        }
        ps += __shfl_xor(ps, 32);
        lsum += ps;

        // ---- PV: P fragments in-register via permlane32_swap ----
        __builtin_amdgcn_s_setprio(1);
        #pragma unroll
        for (int ks = 0; ks < 4; ++ks) {
          if (ks >= 2 && !full) continue;
          u32 a0 = U[4 * ks + 0], a1 = U[4 * ks + 1];
          u32 b0 = U[4 * ks + 2], b1 = U[4 * ks + 3];
          asm("v_permlane32_swap_b32 %0, %1" : "+v"(a0), "+v"(b0));
          asm("v_permlane32_swap_b32 %0, %1" : "+v"(a1), "+v"(b1));
          u32x4 t4; t4.x = a0; t4.y = a1; t4.z = b0; t4.w = b1;
          f16x8 pa = __builtin_bit_cast(f16x8, t4);
          int dcv = (8 * ks + 4 * lg2) ^ swk;
          #pragma unroll
          for (int n = 0; n < 4; ++n) {
            O[n] = MFMA(pa, ld_f16x8(VB + (size_t)(32 * n + l31) * 32 + dcv), O[n]);
          }
        }
        __builtin_amdgcn_s_setprio(0);
      }

      if (more) store_stage(s ^ 1);
      __syncthreads();
    }

    // ---------- epilogue ----------
    float inv = 1.0f / lsum;
    #pragma unroll
    for (int r = 0; r < 16; ++r) {
      int rq = (r & 3) + 8 * (r >> 2) + 4 * lg2;
      float fi = __shfl(inv, rq);
      float* orow = Og + (cbase + qs * 256 + w * 32 + rq) * 2048 + hoff + l31;
      orow[0]  = O[0][r] * fi;
      orow[32] = O[1][r] * fi;
      orow[64] = O[2][r] * fi;
      orow[96] = O[3][r] * fi;
    }
  }
}

// ================= fallback (R4/R6, passed) =================
#define KSTR 66
#define VSTR 34
#define KBUF (64 * KSTR)
#define STG  (KBUF + 128 * VSTR)

__global__ __launch_bounds__(512, 2)
void chunked_attn_fb(const float* __restrict__ Qg, const float* __restrict__ Kg,
                     const float* __restrict__ Vg, float* __restrict__ Og,
                     const float* __restrict__ tab) {
  __shared__ __align__(16) u32 lds[2 * STG];

  const int bx  = blockIdx.x;
  const int h   = bx & 15;
  const int p   = (bx >> 4) & 1;
  const int c   = (bx >> 5) & 3;
  const int b   = bx >> 7;
  const int tid = threadIdx.x;
  const int w   = tid >> 6;
  const int lane= tid & 63;
  const int l31 = lane & 31;
  const int lg2 = lane >> 5;

  const size_t cbase = (size_t)(b * Ll + c * 1024);
  const size_t hoff  = (size_t)h * 128;
  const int tb = c * 1024;

  f32x2 pk[8], pva[4], pvb[4];

  auto issue = [&](int j) {
    const float* kb_ = Kg + (cbase + (size_t)j * 64) * 2048 + hoff;
    const float* vb_ = Vg + (cbase + (size_t)j * 64) * 2048 + hoff;
    #pragma unroll
    for (int r = 0; r < 8; ++r)
      pk[r] = ld_f32x2(kb_ + (size_t)(8 * w + r) * 2048 + 2 * lane);
    #pragma unroll
    for (int rp = 0; rp < 4; ++rp) {
      const float* vr = vb_ + (size_t)(8 * w + 2 * rp) * 2048 + 2 * lane;
      pva[rp] = ld_f32x2(vr);
      pvb[rp] = ld_f32x2(vr + 2048);
    }
  };

  auto xform = [&](int j, int s) {
    u32* KB = lds + s * STG;
    u32* VB = KB + KBUF;
    const float* tbase = tab + (size_t)(tb + j * 64) * 128 + 4 * l31;
    f32x4 cs[8];
    #pragma unroll
    for (int r = 0; r < 8; ++r)
      cs[r] = ld_f32x4(tbase + (size_t)(8 * w + r) * 128);
    const float sgn = (lane < 32) ? -1.0f : 1.0f;
    #pragma unroll
    for (int r = 0; r < 8; ++r) {
      float a0 = pk[r].x, a1 = pk[r].y;
      float p0 = __shfl_xor(a0, 32), p1 = __shfl_xor(a1, 32);
      float o0 = a0 * cs[r].x + sgn * (p0 * cs[r].y);
      float o1 = a1 * cs[r].z + sgn * (p1 * cs[r].w);
      KB[(8 * w + r) * KSTR + lane] = packh((_Float16)o0, (_Float16)o1);
    }
    #pragma unroll
    for (int rp = 0; rp < 4; ++rp) {
      int kp = 4 * w + rp;
      VB[(2 * lane) * VSTR + kp]     = packh((_Float16)pva[rp].x, (_Float16)pvb[rp].x);
      VB[(2 * lane + 1) * VSTR + kp] = packh((_Float16)pva[rp].y, (_Float16)pvb[rp].y);
    }
  };

  #pragma unroll 1
  for (int sp = 0; sp < 2; ++sp) {
    const int qs = sp ? p : (3 - p);
    const int qrow = qs * 256 + w * 32 + l31;

    const float* qbase = Qg + (cbase + qrow) * 2048 + hoff;
    float xq[8][8];
    #pragma unroll
    for (int ds = 0; ds < 8; ++ds) {
      const float* ptr = qbase + ds * 16 + lg2 * 8;
      f32x4 v0 = ld_f32x4(ptr);
      f32x4 v1 = ld_f32x4(ptr + 4);
      xq[ds][0]=v0.x; xq[ds][1]=v0.y; xq[ds][2]=v0.z; xq[ds][3]=v0.w;
      xq[ds][4]=v1.x; xq[ds][5]=v1.y; xq[ds][6]=v1.z; xq[ds][7]=v1.w;
    }
    const float* trowq = tab + (size_t)(tb + qrow) * 128 + lg2 * 16;
    #pragma unroll
    for (int ds = 0; ds < 4; ++ds) {
      #pragma unroll
      for (int i2 = 0; i2 < 4; ++i2) {
        f32x4 cs = ld_f32x4(trowq + ds * 32 + i2 * 4);
        int i0 = 2 * i2;
        float a0 = xq[ds][i0],     b0 = xq[ds + 4][i0];
        xq[ds][i0]     = a0 * cs.x - b0 * cs.y;
        xq[ds + 4][i0] = b0 * cs.x + a0 * cs.y;
        float a1 = xq[ds][i0 + 1], b1 = xq[ds + 4][i0 + 1];
        xq[ds][i0 + 1]     = a1 * cs.z - b1 * cs.w;
        xq[ds + 4][i0 + 1] = b1 * cs.z + a1 * cs.w;
      }
    }
    f16x8 qh[8];
    #pragma unroll
    for (int ds = 0; ds < 8; ++ds)
      #pragma unroll
      for (int i = 0; i < 8; ++i)
        qh[ds][i] = (_Float16)(xq[ds][i] * QSCALE);

    f32x16 O[4];
    #pragma unroll
    for (int n = 0; n < 4; ++n) O[n] = (f32x16)0.0f;
    float m2 = -1e30f, lsum = 0.0f;
    const int  nt    = 4 * (qs + 1);
    const int  jmaxw = 4 * qs + (w >> 1);
    const bool oddw  = w & 1;

    issue(0);
    xform(0, 0);
    __syncthreads();

    for (int j = 0; j < nt; ++j) {
      const int s = j & 1;
      const bool more = (j + 1 < nt);
      if (more) issue(j + 1);

      if (j <= jmaxw) {
        const bool full = oddw || (j < jmaxw);
        const u32* KB = lds + s * STG;
        const u32* VB = KB + KBUF;
        const u32* kr0 = KB + (size_t)l31 * KSTR + lg2 * 4;
        const u32* kr1 = kr0 + (size_t)32 * KSTR;

        f32x16 S0 = (f32x16)0.0f, S1 = (f32x16)0.0f;
        __builtin_amdgcn_s_setprio(1);
        #pragma unroll
        for (int ds = 0; ds < 8; ++ds) {
          S0 = MFMA(ld_frag(kr0 + ds * 8), qh[ds], S0);
          if (full) S1 = MFMA(ld_frag(kr1 + ds * 8), qh[ds], S1);
        }
        __builtin_amdgcn_s_setprio(0);

        if (j == jmaxw) {
          #pragma unroll
          for (int r = 0; r < 16; ++r) {
            int crow = (r & 3) + 8 * (r >> 2) + 4 * lg2;
            if (crow > l31) { if (oddw) S1[r] = -1e30f; else S0[r] = -1e30f; }
          }
        }

        float tm = S0[0];
        #pragma unroll
        for (int r = 1; r < 16; ++r) tm = fmaxf(tm, S0[r]);
        if (full) {
          #pragma unroll
          for (int r = 0; r < 16; ++r) tm = fmaxf(tm, S1[r]);
        }
        tm = fmaxf(tm, __shfl_xor(tm, 32));
        if (!__all(tm <= m2 + 8.0f)) {
          float m2n = fmaxf(m2, tm);
          float fac = exp2f(m2 - m2n);
          lsum *= fac;
          #pragma unroll
          for (int r = 0; r < 16; ++r) {
            int rq = (r & 3) + 8 * (r >> 2) + 4 * lg2;
            float fr = __shfl(fac, rq);
            O[0][r] *= fr; O[1][r] *= fr; O[2][r] *= fr; O[3][r] *= fr;
          }
          m2 = m2n;
        }
        u32 U[16];
        float ps = 0.0f;
        #pragma unroll
        for (int t = 0; t < 8; ++t) {
          float e0 = exp2f(S0[2 * t]     - m2);
          float e1 = exp2f(S0[2 * t + 1] - m2);
          U[t] = packh((_Float16)e0, (_Float16)e1);
          ps += e0 + e1;
        }
        if (full) {
          #pragma unroll
          for (int t = 0; t < 8; ++t) {
            float e0 = exp2f(S1[2 * t]     - m2);
            float e1 = exp2f(S1[2 * t + 1] - m2);
            U[8 + t] = packh((_Float16)e0, (_Float16)e1);
            ps += e0 + e1;
          }
        }
        ps += __shfl_xor(ps, 32);
        lsum += ps;

        __builtin_amdgcn_s_setprio(1);
        #pragma unroll
        for (int ks = 0; ks < 4; ++ks) {
          if (ks >= 2 && !full) continue;
          u32 a0 = U[4 * ks + 0], a1 = U[4 * ks + 1];
          u32 b0 = U[4 * ks + 2], b1 = U[4 * ks + 3];
          asm("v_permlane32_swap_b32 %0, %1" : "+v"(a0), "+v"(b0));
          asm("v_permlane32_swap_b32 %0, %1" : "+v"(a1), "+v"(b1));
          u32x4 t4; t4.x = a0; t4.y = a1; t4.z = b0; t4.w = b1;
          f16x8 pa = __builtin_bit_cast(f16x8, t4);
          #pragma unroll
          for (int n = 0; n < 4; ++n) {
            const u32* vp = VB + (size_t)(32 * n + l31) * VSTR + 8 * ks + 4 * lg2;
            O[n] = MFMA(pa, ld_frag(vp), O[n]);
          }
        }
        __builtin_amdgcn_s_setprio(0);
      }

      if (more) xform(j + 1, s ^ 1);
      __syncthreads();
    }

    float inv = 1.0f / lsum;
    #pragma unroll
    for (int r = 0; r < 16; ++r) {
      int rq = (r & 3) + 8 * (r >> 2) + 4 * lg2;
      float fi = __shfl(inv, rq);
      float* orow = Og + (cbase + qs * 256 + w * 32 + rq) * 2048 + hoff + l31;
      orow[0]  = O[0][r] * fi;
      orow[32] = O[1][r] * fi;
      orow[64] = O[2][r] * fi;
      orow[96] = O[3][r] * fi;
    }
  }
}

extern "C" void kernel_launch(void* const* d_in, const int* in_sizes, int n_in,
                              void* d_out, int out_size, void* d_ws, size_t ws_size,
                              hipStream_t stream) {
  const float* q = (const float*)d_in[0];
  const float* k = (const float*)d_in[1];
  const float* v = (const float*)d_in[2];
  const int* start = (const int*)d_in[3];
  float* out = (float*)d_out;

  float* tab = (float*)d_ws;                          // 2 MB
  const size_t KH_OFFB = 2u * 1024 * 1024;            // 64 MB
  const size_t VT_OFFB = KH_OFFB + 64u * 1024 * 1024; // 64 MB
  const size_t NEED = VT_OFFB + 64u * 1024 * 1024;    // 130 MB total

  rope_table_k<<<dim3(1024), dim3(256), 0, stream>>>(start, tab);

  if (ws_size >= NEED) {
    u32* Kh = (u32*)((char*)d_ws + KH_OFFB);
    u32* VT = (u32*)((char*)d_ws + VT_OFFB);
    prep_merged_kernel<<<dim3(69632), dim3(256), 0, stream>>>(k, v, tab, Kh, VT);
    attn_f16_k<<<dim3(512), dim3(512), 0, stream>>>(q, Kh, VT, out, tab);
  } else {
    chunked_attn_fb<<<dim3(512), dim3(512), 0, stream>>>(q, k, v, out, tab);
  }
}

// Round 17
// 271.130 us; speedup vs baseline: 1.0188x; 1.0018x over previous
//
#include <hip/hip_runtime.h>

// ChunkedSelfAttention (RoPE + per-chunk causal SDPA), MI355X gfx950.
// FINAL: session-best config (measured 269.9-271.6 us across 3 runs).
// Structure: merged f16 prepass (rope-K + V^T, pre-swizzled LDS-ready
// layout in d_ws) + 8-wave flash attention (64-key tiles, double-buffered
// reg staging, swapped-QK in-register softmax, permlane32 P fragments,
// diagonal half-skip, T13 deferred rescale). Ladder: 497->316->273->270us.

typedef __attribute__((ext_vector_type(2)))  float     f32x2;
typedef __attribute__((ext_vector_type(4)))  float     f32x4;
typedef __attribute__((ext_vector_type(16))) float     f32x16;
typedef __attribute__((ext_vector_type(8)))  _Float16  f16x8;
typedef unsigned int   u32;
typedef unsigned short u16;
typedef __attribute__((ext_vector_type(4))) unsigned int u32x4;

#define MFMA(a, b, c) __builtin_amdgcn_mfma_f32_32x32x16_f16(a, b, c, 0, 0, 0)

constexpr int Ll = 4096;
constexpr float QSCALE = 0.08838834764831845f * 1.4426950408889634f; // 1/sqrt(128)*log2(e)

__device__ __forceinline__ f32x4 ld_f32x4(const void* p) { f32x4 v; __builtin_memcpy(&v, p, 16); return v; }
__device__ __forceinline__ f32x2 ld_f32x2(const void* p) { f32x2 v; __builtin_memcpy(&v, p, 8);  return v; }
__device__ __forceinline__ u32x4 ld_u32x4(const void* p) { u32x4 v; __builtin_memcpy(&v, p, 16); return v; }
__device__ __forceinline__ void  st_u32x4(void* p, u32x4 v) { __builtin_memcpy(p, &v, 16); }
__device__ __forceinline__ f16x8 ld_f16x8(const void* p) { f16x8 v; __builtin_memcpy(&v, p, 16); return v; }
__device__ __forceinline__ f16x8 ld_frag(const u32* dwp) {
  f16x8 v;
  __builtin_memcpy(&v, dwp, 8);
  __builtin_memcpy(((char*)&v) + 8, dwp + 2, 8);
  return v;
}
__device__ __forceinline__ u32 packh(_Float16 a, _Float16 b) {
  return (u32)__builtin_bit_cast(u16, a) | ((u32)__builtin_bit_cast(u16, b) << 16);
}

// ---- cos/sin table: tab[t*128 + 2*hid] = {cos, sin}, ang = (t+start)*inv_freq ----
__global__ void rope_table_k(const int* __restrict__ startp, float* __restrict__ tab) {
  int idx = blockIdx.x * 256 + threadIdx.x;
  int t = idx >> 6, hid = idx & 63;
  float a = (float)hid * (-0.14391156831212878f);
  float invf = expf(a);
  float ang = (float)(t + startp[0]) * invf;
  tab[2 * idx]     = cosf(ang);
  tab[2 * idx + 1] = sinf(ang);
}

// ---- merged prepass: blocks [0,65536) = K (roped f16, swizzled);
//      blocks [65536,69632) = V^T f16 swizzled. ----
__global__ __launch_bounds__(256)
void prep_merged_kernel(const float* __restrict__ Kg, const float* __restrict__ Vg,
                        const float* __restrict__ tab, u32* __restrict__ Kh,
                        u32* __restrict__ VT) {
  __shared__ __align__(16) u32 tile[4096];
  const int bx = blockIdx.x;
  if (bx < 65536) {
    const int R    = bx * 4 + (threadIdx.x >> 6);
    const int lane = threadIdx.x & 63;
    const int h  = R & 15;
    const int bt = R >> 4;
    const int b  = bt >> 12;
    const int t  = bt & 4095;
    const int c  = t >> 10;
    const int j  = (t >> 6) & 15;
    const int row = t & 63;
    const int GID = (b * 4 + c) * 16 + h;
    const int sw  = (row & 7) << 4;
    const int dc  = ((4 * lane) ^ sw) >> 1;
    f32x2 a = ld_f32x2(Kg + (size_t)R * 128 + dc);
    float p0 = __shfl_xor(a.x, 32);
    float p1 = __shfl_xor(a.y, 32);
    f32x4 cs = ld_f32x4(tab + (size_t)t * 128 + 2 * (dc & 63));
    const float sgn = (dc < 64) ? -1.0f : 1.0f;
    float o0 = a.x * cs.x + sgn * (p0 * cs.y);
    float o1 = a.y * cs.z + sgn * (p1 * cs.w);
    Kh[((size_t)(GID * 16 + j) * 64 + row) * 64 + lane] = packh((_Float16)o0, (_Float16)o1);
  } else {
    const int gj  = bx - 65536;
    const int GID = gj >> 4, j = gj & 15;
    const int h = GID & 15, c = (GID >> 4) & 3, b = GID >> 6;
    const int tid = threadIdx.x;
    const size_t rowbase = ((size_t)(b * 4096 + c * 1024 + j * 64)) * 16 + h;
    const int k  = tid >> 2;
    const int dq = tid & 3;
    u16* t16 = (u16*)tile;
    #pragma unroll
    for (int it = 0; it < 8; ++it) {
      int dv0 = dq * 4 + 16 * it;
      f32x4 v4 = ld_f32x4(Vg + (rowbase + (size_t)k * 16) * 128 + dv0);
      #pragma unroll
      for (int u = 0; u < 4; ++u) {
        int dv = dv0 + u;
        int ci = k ^ ((dv & 7) << 3);
        t16[dv * 64 + ci] = __builtin_bit_cast(u16, (_Float16)v4[u]);
      }
    }
    __syncthreads();
    const u32* tsrc = tile + 16 * tid;
    u32* dst = VT + (size_t)gj * 4096 + 16 * tid;
    #pragma unroll
    for (int u = 0; u < 4; ++u) st_u32x4(dst + 4 * u, ld_u32x4(tsrc + 4 * u));
  }
}

// ================= main attention (best-measured skeleton) =================
__global__ __launch_bounds__(512, 2)
void attn_f16_k(const float* __restrict__ Qg, const u32* __restrict__ Kh,
                const u32* __restrict__ VT, float* __restrict__ Og,
                const float* __restrict__ tab) {
  __shared__ __align__(16) u32 lds[2 * 8192];   // 64 KB, double-buffered

  const int bx  = blockIdx.x;
  const int h   = bx & 15;
  const int p   = (bx >> 4) & 1;
  const int c   = (bx >> 5) & 3;
  const int b   = bx >> 7;
  const int tid = threadIdx.x;
  const int w   = tid >> 6;
  const int lane= tid & 63;
  const int l31 = lane & 31;
  const int lg2 = lane >> 5;

  const size_t cbase = (size_t)(b * Ll + c * 1024);
  const size_t hoff  = (size_t)h * 128;
  const int tb  = c * 1024;
  const int GID = (b * 4 + c) * 16 + h;
  const u32* khg = Kh + (size_t)GID * 16 * 4096;
  const u32* vtg = VT + (size_t)GID * 16 * 4096;

  u32x4 stg[4];
  auto issue = [&](int j) {
    #pragma unroll
    for (int i = 0; i < 4; ++i) {
      int ch = w + 8 * i;                // 32 chunks of 1 KB: 0..15 K, 16..31 VT
      const u32* src = (ch < 16) ? (khg + (size_t)j * 4096 + ch * 256 + 4 * lane)
                                 : (vtg + (size_t)j * 4096 + (ch - 16) * 256 + 4 * lane);
      stg[i] = ld_u32x4(src);
    }
  };
  auto store_stage = [&](int s) {
    u32* dst0 = lds + (size_t)s * 8192;
    #pragma unroll
    for (int i = 0; i < 4; ++i) {
      int ch = w + 8 * i;
      st_u32x4(dst0 + ch * 256 + 4 * lane, stg[i]);
    }
  };

  #pragma unroll 1
  for (int sp = 0; sp < 2; ++sp) {
    const int qs = sp ? p : (3 - p);            // heavy strip first
    const int qrow = qs * 256 + w * 32 + l31;

    // ---------- Q prologue: load f32, rope, scale, f16 ----------
    const float* qbase = Qg + (cbase + qrow) * 2048 + hoff;
    float xq[8][8];
    #pragma unroll
    for (int ds = 0; ds < 8; ++ds) {
      const float* ptr = qbase + ds * 16 + lg2 * 8;
      f32x4 v0 = ld_f32x4(ptr);
      f32x4 v1 = ld_f32x4(ptr + 4);
      xq[ds][0]=v0.x; xq[ds][1]=v0.y; xq[ds][2]=v0.z; xq[ds][3]=v0.w;
      xq[ds][4]=v1.x; xq[ds][5]=v1.y; xq[ds][6]=v1.z; xq[ds][7]=v1.w;
    }
    const float* trowq = tab + (size_t)(tb + qrow) * 128 + lg2 * 16;
    #pragma unroll
    for (int ds = 0; ds < 4; ++ds) {
      #pragma unroll
      for (int i2 = 0; i2 < 4; ++i2) {
        f32x4 cs = ld_f32x4(trowq + ds * 32 + i2 * 4);
        int i0 = 2 * i2;
        float a0 = xq[ds][i0],     b0 = xq[ds + 4][i0];
        xq[ds][i0]     = a0 * cs.x - b0 * cs.y;
        xq[ds + 4][i0] = b0 * cs.x + a0 * cs.y;
        float a1 = xq[ds][i0 + 1], b1 = xq[ds + 4][i0 + 1];
        xq[ds][i0 + 1]     = a1 * cs.z - b1 * cs.w;
        xq[ds + 4][i0 + 1] = b1 * cs.z + a1 * cs.w;
      }
    }
    f16x8 qh[8];
    #pragma unroll
    for (int ds = 0; ds < 8; ++ds)
      #pragma unroll
      for (int i = 0; i < 8; ++i)
        qh[ds][i] = (_Float16)(xq[ds][i] * QSCALE);

    // ---------- state ----------
    f32x16 O[4];
    #pragma unroll
    for (int n = 0; n < 4; ++n) O[n] = (f32x16)0.0f;
    float m2 = -1e30f, lsum = 0.0f;
    const int  nt    = 4 * (qs + 1);
    const int  jmaxw = 4 * qs + (w >> 1);
    const bool oddw  = w & 1;

    issue(0);
    store_stage(0);
    __syncthreads();

    for (int j = 0; j < nt; ++j) {
      const int s = j & 1;
      const bool more = (j + 1 < nt);
      if (more) issue(j + 1);          // global loads fly under compute

      if (j <= jmaxw) {
        const bool full = oddw || (j < jmaxw);
        const u32* KB = lds + (size_t)s * 8192;
        const u32* VB = KB + 4096;
        const u32* kr0 = KB + (size_t)l31 * 64;
        const u32* kr1 = kr0 + 32 * 64;
        const int  swk = (l31 & 7) << 2;      // dword-col XOR

        // ---- QK^T (swapped): S^T[k][q] = K . Q^T ----
        f32x16 S0 = (f32x16)0.0f, S1 = (f32x16)0.0f;
        __builtin_amdgcn_s_setprio(1);
        #pragma unroll
        for (int ds = 0; ds < 8; ++ds) {
          int dc = (8 * ds + 4 * lg2) ^ swk;
          S0 = MFMA(ld_f16x8(kr0 + dc), qh[ds], S0);
          if (full) S1 = MFMA(ld_f16x8(kr1 + dc), qh[ds], S1);
        }
        __builtin_amdgcn_s_setprio(0);

        // ---- causal mask (diagonal tile only) ----
        if (j == jmaxw) {
          #pragma unroll
          for (int r = 0; r < 16; ++r) {
            int crow = (r & 3) + 8 * (r >> 2) + 4 * lg2;
            if (crow > l31) { if (oddw) S1[r] = -1e30f; else S0[r] = -1e30f; }
          }
        }

        // ---- online softmax (base-2), T13 deferred rescale ----
        float tm = S0[0];
        #pragma unroll
        for (int r = 1; r < 16; ++r) tm = fmaxf(tm, S0[r]);
        if (full) {
          #pragma unroll
          for (int r = 0; r < 16; ++r) tm = fmaxf(tm, S1[r]);
        }
        tm = fmaxf(tm, __shfl_xor(tm, 32));
        if (!__all(tm <= m2 + 8.0f)) {
          float m2n = fmaxf(m2, tm);
          float fac = exp2f(m2 - m2n);
          lsum *= fac;
          #pragma unroll
          for (int r = 0; r < 16; ++r) {
            int rq = (r & 3) + 8 * (r >> 2) + 4 * lg2;
            float fr = __shfl(fac, rq);
            O[0][r] *= fr; O[1][r] *= fr; O[2][r] *= fr; O[3][r] *= fr;
          }
          m2 = m2n;
        }
        u32 U[16];
        float ps = 0.0f;
        #pragma unroll
        for (int t = 0; t < 8; ++t) {
          float e0 = exp2f(S0[2 * t]     - m2);
          float e1 = exp2f(S0[2 * t + 1] - m2);
          U[t] = packh((_Float16)e0, (_Float16)e1);
          ps += e0 + e1;
        }
        if (full) {
          #pragma unroll
          for (int t = 0; t < 8; ++t) {
            float e0 = exp2f(S1[2 * t]     - m2);
            float e1 = exp2f(S1[2 * t + 1] - m2);
            U[8 + t] = packh((_Float16)e0, (_Float16)e1);
            ps += e0 + e1;
          }
        }
        ps += __shfl_xor(ps, 32);
        lsum += ps;

        // ---- PV: P fragments in-register via permlane32_swap ----
        __builtin_amdgcn_s_setprio(1);
        #pragma unroll
        for (int ks = 0; ks < 4; ++ks) {
          if (ks >= 2 && !full) continue;
          u32 a0 = U[4 * ks + 0], a1 = U[4 * ks + 1];
          u32 b0 = U[4 * ks + 2], b1 = U[4 * ks + 3];
          asm("v_permlane32_swap_b32 %0, %1" : "+v"(a0), "+v"(b0));
          asm("v_permlane32_swap_b32 %0, %1" : "+v"(a1), "+v"(b1));
          u32x4 t4; t4.x = a0; t4.y = a1; t4.z = b0; t4.w = b1;
          f16x8 pa = __builtin_bit_cast(f16x8, t4);
          int dcv = (8 * ks + 4 * lg2) ^ swk;
          #pragma unroll
          for (int n = 0; n < 4; ++n) {
            O[n] = MFMA(pa, ld_f16x8(VB + (size_t)(32 * n + l31) * 32 + dcv), O[n]);
          }
        }
        __builtin_amdgcn_s_setprio(0);
      }

      if (more) store_stage(s ^ 1);
      __syncthreads();
    }

    // ---------- epilogue ----------
    float inv = 1.0f / lsum;
    #pragma unroll
    for (int r = 0; r < 16; ++r) {
      int rq = (r & 3) + 8 * (r >> 2) + 4 * lg2;
      float fi = __shfl(inv, rq);
      float* orow = Og + (cbase + qs * 256 + w * 32 + rq) * 2048 + hoff + l31;
      orow[0]  = O[0][r] * fi;
      orow[32] = O[1][r] * fi;
      orow[64] = O[2][r] * fi;
      orow[96] = O[3][r] * fi;
    }
  }
}

// ================= fallback (R4/R6, passed) =================
#define KSTR 66
#define VSTR 34
#define KBUF (64 * KSTR)
#define STG  (KBUF + 128 * VSTR)

__global__ __launch_bounds__(512, 2)
void chunked_attn_fb(const float* __restrict__ Qg, const float* __restrict__ Kg,
                     const float* __restrict__ Vg, float* __restrict__ Og,
                     const float* __restrict__ tab) {
  __shared__ __align__(16) u32 lds[2 * STG];

  const int bx  = blockIdx.x;
  const int h   = bx & 15;
  const int p   = (bx >> 4) & 1;
  const int c   = (bx >> 5) & 3;
  const int b   = bx >> 7;
  const int tid = threadIdx.x;
  const int w   = tid >> 6;
  const int lane= tid & 63;
  const int l31 = lane & 31;
  const int lg2 = lane >> 5;

  const size_t cbase = (size_t)(b * Ll + c * 1024);
  const size_t hoff  = (size_t)h * 128;
  const int tb = c * 1024;

  f32x2 pk[8], pva[4], pvb[4];

  auto issue = [&](int j) {
    const float* kb_ = Kg + (cbase + (size_t)j * 64) * 2048 + hoff;
    const float* vb_ = Vg + (cbase + (size_t)j * 64) * 2048 + hoff;
    #pragma unroll
    for (int r = 0; r < 8; ++r)
      pk[r] = ld_f32x2(kb_ + (size_t)(8 * w + r) * 2048 + 2 * lane);
    #pragma unroll
    for (int rp = 0; rp < 4; ++rp) {
      const float* vr = vb_ + (size_t)(8 * w + 2 * rp) * 2048 + 2 * lane;
      pva[rp] = ld_f32x2(vr);
      pvb[rp] = ld_f32x2(vr + 2048);
    }
  };

  auto xform = [&](int j, int s) {
    u32* KB = lds + s * STG;
    u32* VB = KB + KBUF;
    const float* tbase = tab + (size_t)(tb + j * 64) * 128 + 4 * l31;
    f32x4 cs[8];
    #pragma unroll
    for (int r = 0; r < 8; ++r)
      cs[r] = ld_f32x4(tbase + (size_t)(8 * w + r) * 128);
    const float sgn = (lane < 32) ? -1.0f : 1.0f;
    #pragma unroll
    for (int r = 0; r < 8; ++r) {
      float a0 = pk[r].x, a1 = pk[r].y;
      float p0 = __shfl_xor(a0, 32), p1 = __shfl_xor(a1, 32);
      float o0 = a0 * cs[r].x + sgn * (p0 * cs[r].y);
      float o1 = a1 * cs[r].z + sgn * (p1 * cs[r].w);
      KB[(8 * w + r) * KSTR + lane] = packh((_Float16)o0, (_Float16)o1);
    }
    #pragma unroll
    for (int rp = 0; rp < 4; ++rp) {
      int kp = 4 * w + rp;
      VB[(2 * lane) * VSTR + kp]     = packh((_Float16)pva[rp].x, (_Float16)pvb[rp].x);
      VB[(2 * lane + 1) * VSTR + kp] = packh((_Float16)pva[rp].y, (_Float16)pvb[rp].y);
    }
  };

  #pragma unroll 1
  for (int sp = 0; sp < 2; ++sp) {
    const int qs = sp ? p : (3 - p);
    const int qrow = qs * 256 + w * 32 + l31;

    const float* qbase = Qg + (cbase + qrow) * 2048 + hoff;
    float xq[8][8];
    #pragma unroll
    for (int ds = 0; ds < 8; ++ds) {
      const float* ptr = qbase + ds * 16 + lg2 * 8;
      f32x4 v0 = ld_f32x4(ptr);
      f32x4 v1 = ld_f32x4(ptr + 4);
      xq[ds][0]=v0.x; xq[ds][1]=v0.y; xq[ds][2]=v0.z; xq[ds][3]=v0.w;
      xq[ds][4]=v1.x; xq[ds][5]=v1.y; xq[ds][6]=v1.z; xq[ds][7]=v1.w;
    }
    const float* trowq = tab + (size_t)(tb + qrow) * 128 + lg2 * 16;
    #pragma unroll
    for (int ds = 0; ds < 4; ++ds) {
      #pragma unroll
      for (int i2 = 0; i2 < 4; ++i2) {
        f32x4 cs = ld_f32x4(trowq + ds * 32 + i2 * 4);
        int i0 = 2 * i2;
        float a0 = xq[ds][i0],     b0 = xq[ds + 4][i0];
        xq[ds][i0]     = a0 * cs.x - b0 * cs.y;
        xq[ds + 4][i0] = b0 * cs.x + a0 * cs.y;
        float a1 = xq[ds][i0 + 1], b1 = xq[ds + 4][i0 + 1];
        xq[ds][i0 + 1]     = a1 * cs.z - b1 * cs.w;
        xq[ds + 4][i0 + 1] = b1 * cs.z + a1 * cs.w;
      }
    }
    f16x8 qh[8];
    #pragma unroll
    for (int ds = 0; ds < 8; ++ds)
      #pragma unroll
      for (int i = 0; i < 8; ++i)
        qh[ds][i] = (_Float16)(xq[ds][i] * QSCALE);

    f32x16 O[4];
    #pragma unroll
    for (int n = 0; n < 4; ++n) O[n] = (f32x16)0.0f;
    float m2 = -1e30f, lsum = 0.0f;
    const int  nt    = 4 * (qs + 1);
    const int  jmaxw = 4 * qs + (w >> 1);
    const bool oddw  = w & 1;

    issue(0);
    xform(0, 0);
    __syncthreads();

    for (int j = 0; j < nt; ++j) {
      const int s = j & 1;
      const bool more = (j + 1 < nt);
      if (more) issue(j + 1);

      if (j <= jmaxw) {
        const bool full = oddw || (j < jmaxw);
        const u32* KB = lds + s * STG;
        const u32* VB = KB + KBUF;
        const u32* kr0 = KB + (size_t)l31 * KSTR + lg2 * 4;
        const u32* kr1 = kr0 + (size_t)32 * KSTR;

        f32x16 S0 = (f32x16)0.0f, S1 = (f32x16)0.0f;
        __builtin_amdgcn_s_setprio(1);
        #pragma unroll
        for (int ds = 0; ds < 8; ++ds) {
          S0 = MFMA(ld_frag(kr0 + ds * 8), qh[ds], S0);
          if (full) S1 = MFMA(ld_frag(kr1 + ds * 8), qh[ds], S1);
        }
        __builtin_amdgcn_s_setprio(0);

        if (j == jmaxw) {
          #pragma unroll
          for (int r = 0; r < 16; ++r) {
            int crow = (r & 3) + 8 * (r >> 2) + 4 * lg2;
            if (crow > l31) { if (oddw) S1[r] = -1e30f; else S0[r] = -1e30f; }
          }
        }

        float tm = S0[0];
        #pragma unroll
        for (int r = 1; r < 16; ++r) tm = fmaxf(tm, S0[r]);
        if (full) {
          #pragma unroll
          for (int r = 0; r < 16; ++r) tm = fmaxf(tm, S1[r]);
        }
        tm = fmaxf(tm, __shfl_xor(tm, 32));
        if (!__all(tm <= m2 + 8.0f)) {
          float m2n = fmaxf(m2, tm);
          float fac = exp2f(m2 - m2n);
          lsum *= fac;
          #pragma unroll
          for (int r = 0; r < 16; ++r) {
            int rq = (r & 3) + 8 * (r >> 2) + 4 * lg2;
            float fr = __shfl(fac, rq);
            O[0][r] *= fr; O[1][r] *= fr; O[2][r] *= fr; O[3][r] *= fr;
          }
          m2 = m2n;
        }
        u32 U[16];
        float ps = 0.0f;
        #pragma unroll
        for (int t = 0; t < 8; ++t) {
          float e0 = exp2f(S0[2 * t]     - m2);
          float e1 = exp2f(S0[2 * t + 1] - m2);
          U[t] = packh((_Float16)e0, (_Float16)e1);
          ps += e0 + e1;
        }
        if (full) {
          #pragma unroll
          for (int t = 0; t < 8; ++t) {
            float e0 = exp2f(S1[2 * t]     - m2);
            float e1 = exp2f(S1[2 * t + 1] - m2);
            U[8 + t] = packh((_Float16)e0, (_Float16)e1);
            ps += e0 + e1;
          }
        }
        ps += __shfl_xor(ps, 32);
        lsum += ps;

        __builtin_amdgcn_s_setprio(1);
        #pragma unroll
        for (int ks = 0; ks < 4; ++ks) {
          if (ks >= 2 && !full) continue;
          u32 a0 = U[4 * ks + 0], a1 = U[4 * ks + 1];
          u32 b0 = U[4 * ks + 2], b1 = U[4 * ks + 3];
          asm("v_permlane32_swap_b32 %0, %1" : "+v"(a0), "+v"(b0));
          asm("v_permlane32_swap_b32 %0, %1" : "+v"(a1), "+v"(b1));
          u32x4 t4; t4.x = a0; t4.y = a1; t4.z = b0; t4.w = b1;
          f16x8 pa = __builtin_bit_cast(f16x8, t4);
          #pragma unroll
          for (int n = 0; n < 4; ++n) {
            const u32* vp = VB + (size_t)(32 * n + l31) * VSTR + 8 * ks + 4 * lg2;
            O[n] = MFMA(pa, ld_frag(vp), O[n]);
          }
        }
        __builtin_amdgcn_s_setprio(0);
      }

      if (more) xform(j + 1, s ^ 1);
      __syncthreads();
    }

    float inv = 1.0f / lsum;
    #pragma unroll
    for (int r = 0; r < 16; ++r) {
      int rq = (r & 3) + 8 * (r >> 2) + 4 * lg2;
      float fi = __shfl(inv, rq);
      float* orow = Og + (cbase + qs * 256 + w * 32 + rq) * 2048 + hoff + l31;
      orow[0]  = O[0][r] * fi;
      orow[32] = O[1][r] * fi;
      orow[64] = O[2][r] * fi;
      orow[96] = O[3][r] * fi;
    }
  }
}

extern "C" void kernel_launch(void* const* d_in, const int* in_sizes, int n_in,
                              void* d_out, int out_size, void* d_ws, size_t ws_size,
                              hipStream_t stream) {
  const float* q = (const float*)d_in[0];
  const float* k = (const float*)d_in[1];
  const float* v = (const float*)d_in[2];
  const int* start = (const int*)d_in[3];
  float* out = (float*)d_out;

  float* tab = (float*)d_ws;                          // 2 MB
  const size_t KH_OFFB = 2u * 1024 * 1024;            // 64 MB
  const size_t VT_OFFB = KH_OFFB + 64u * 1024 * 1024; // 64 MB
  const size_t NEED = VT_OFFB + 64u * 1024 * 1024;    // 130 MB total

  rope_table_k<<<dim3(1024), dim3(256), 0, stream>>>(start, tab);

  if (ws_size >= NEED) {
    u32* Kh = (u32*)((char*)d_ws + KH_OFFB);
    u32* VT = (u32*)((char*)d_ws + VT_OFFB);
    prep_merged_kernel<<<dim3(69632), dim3(256), 0, stream>>>(k, v, tab, Kh, VT);
    attn_f16_k<<<dim3(512), dim3(512), 0, stream>>>(q, Kh, VT, out, tab);
  } else {
    chunked_attn_fb<<<dim3(512), dim3(512), 0, stream>>>(q, k, v, out, tab);
  }
}